// Round 11
// baseline (313.689 us; speedup 1.0000x reference)
//
#include <hip/hip_runtime.h>
#include <math.h>

#define N_NODES 50000
#define F_IN 128
#define NE 800000
#define NH1 8
#define ND1 16
#define ND2 8
#define NEG 0.2f
#define ZLEN (N_NODES * ND2)      // 400000
#define NBLK 196                  // ceil(50000/256); also the co-resident fused grid
#define FC1_RPB 240
#define FC1_NB 1667               // ceil(400000/240)

typedef __attribute__((ext_vector_type(8))) short bf16x8;   // 8 bf16 (4 VGPRs)
typedef __attribute__((ext_vector_type(4))) float f32x4;
typedef __attribute__((ext_vector_type(2))) float f32x2;

__device__ __forceinline__ float lrelu(float v) { return v > 0.f ? v : NEG * v; }
__device__ __forceinline__ float elu1(float v)  { return v > 0.f ? v : (__expf(v) - 1.f); }

__device__ __forceinline__ unsigned short f2bf(float f) {
    union { float f; unsigned int i; } c; c.f = f;
    unsigned int u = c.i;
    return (unsigned short)((u + 0x7FFFu + ((u >> 16) & 1u)) >> 16);
}
// int64-vs-int32 edge dtype: high words of first 4 entries all zero => int64
__device__ __forceinline__ int ei_is64(const int* __restrict__ ei) {
    return ((ei[1] | ei[3] | ei[5] | ei[7]) == 0) ? 1 : 0;
}

// grid barrier for co-resident grids (grid <= 256 blocks). Counter monotonically
// increases across phases; prep_kernel zeroes it every call (determinism).
__device__ __forceinline__ void grid_barrier(int* cnt, int target) {
    __threadfence();
    __syncthreads();
    if (threadIdx.x == 0) {
        atomicAdd(cnt, 1);
        while (atomicAdd(cnt, 0) < target) __builtin_amdgcn_s_sleep(8);
    }
    __syncthreads();
}

// ---------------- prep: W1 -> bf16 swizzled + counts init + barrier zero ----------------
__global__ __launch_bounds__(256) void prep_kernel(const float* __restrict__ W,
                                                   uint4* __restrict__ wbf,
                                                   int* __restrict__ counts,
                                                   int* __restrict__ bars) {
    int i = blockIdx.x * 256 + threadIdx.x;
    if (i < N_NODES) counts[i] = 1;   // self-loop
    if (i < 2) bars[i] = 0;           // grid-barrier counters (csr, conv2)
    if (i < 2048) {
        int col = i >> 4, kc = i & 15;
        unsigned int u[4];
        #pragma unroll
        for (int jj = 0; jj < 4; ++jj) {
            unsigned int lo = f2bf(W[(kc * 8 + 2 * jj) * 128 + col]);
            unsigned int hi = f2bf(W[(kc * 8 + 2 * jj + 1) * 128 + col]);
            u[jj] = lo | (hi << 16);
        }
        uint4 v; v.x = u[0]; v.y = u[1]; v.z = u[2]; v.w = u[3];
        wbf[col * 16 + (kc ^ (col & 15))] = v;
    }
}

// ---------------- CSR build, single kernel: hist -> block sums -> scan -> fill ----------
__global__ __launch_bounds__(256) void csr_kernel(const int* __restrict__ ei,
                                                  int* __restrict__ counts,
                                                  int* __restrict__ bsum,
                                                  int* __restrict__ rowptr,
                                                  int* __restrict__ cursor,
                                                  int* __restrict__ esrc,
                                                  int* __restrict__ bar) {
    __shared__ int wsum[4];
    __shared__ int wpre[4];
    __shared__ int s_boff;
    const int t = threadIdx.x;
    const int b = blockIdx.x;
    const int gtid = b * 256 + t;
    const int nthr = NBLK * 256;              // 50176
    const int NQ = NE / 4;                    // 200000
    const int is64 = ei_is64(ei);

    // ---- phase A: histogram; cache this thread's edge quads in registers ----
    int4 sq[4], dq[4];
    int nq = 0;
    #pragma unroll
    for (int k = 0; k < 4; ++k) {
        int q = gtid + k * nthr;
        if (q < NQ) {
            int4 s4, d4;
            if (is64) {
                const int4* ps = reinterpret_cast<const int4*>(ei);
                const int4* pd = reinterpret_cast<const int4*>(ei + 2 * NE);
                int4 sa = ps[q * 2], sb = ps[q * 2 + 1];
                int4 da = pd[q * 2], db = pd[q * 2 + 1];
                s4 = make_int4(sa.x, sa.z, sb.x, sb.z);
                d4 = make_int4(da.x, da.z, db.x, db.z);
            } else {
                s4 = reinterpret_cast<const int4*>(ei)[q];
                d4 = reinterpret_cast<const int4*>(ei + NE)[q];
            }
            sq[k] = s4; dq[k] = d4;
            atomicAdd(&counts[d4.x], 1);
            atomicAdd(&counts[d4.y], 1);
            atomicAdd(&counts[d4.z], 1);
            atomicAdd(&counts[d4.w], 1);
            nq = k + 1;
        }
    }
    grid_barrier(bar, NBLK);

    // ---- phase B: per-block sums ----
    {
        int v = (gtid < N_NODES) ? counts[gtid] : 0;
        int r = v;
        #pragma unroll
        for (int off = 32; off; off >>= 1) r += __shfl_down(r, off, 64);
        if ((t & 63) == 0) wsum[t >> 6] = r;
        __syncthreads();
        if (t == 0) bsum[b] = wsum[0] + wsum[1] + wsum[2] + wsum[3];
    }
    grid_barrier(bar, NBLK * 2);

    // ---- phase C: scan (block offset from bsum lookback) ----
    {
        const int lane = t & 63, w = t >> 6;
        int v = (gtid < N_NODES) ? counts[gtid] : 0;
        int incl = v;
        #pragma unroll
        for (int off = 1; off < 64; off <<= 1) {
            int u = __shfl_up(incl, off, 64);
            if (lane >= off) incl += u;
        }
        if (lane == 63) wsum[w] = incl;
        if (t < 64) {
            int s = 0;
            for (int k = t; k < b; k += 64) s += bsum[k];
            #pragma unroll
            for (int off = 32; off; off >>= 1) s += __shfl_down(s, off, 64);
            if (t == 0) s_boff = s;
        }
        __syncthreads();
        if (t == 0) { int s = 0; for (int j = 0; j < 4; ++j) { wpre[j] = s; s += wsum[j]; } }
        __syncthreads();
        incl += wpre[w] + s_boff;
        if (gtid < N_NODES) { rowptr[gtid + 1] = incl; cursor[gtid] = incl - v; }
        if (gtid == 0) rowptr[0] = 0;
    }
    grid_barrier(bar, NBLK * 3);

    // ---- phase D: fill from register-cached quads + self loops ----
    #pragma unroll
    for (int k = 0; k < 4; ++k) {
        if (k < nq) {
            esrc[atomicAdd(&cursor[dq[k].x], 1)] = sq[k].x;
            esrc[atomicAdd(&cursor[dq[k].y], 1)] = sq[k].y;
            esrc[atomicAdd(&cursor[dq[k].z], 1)] = sq[k].z;
            esrc[atomicAdd(&cursor[dq[k].w], 1)] = sq[k].w;
        }
    }
    if (gtid < N_NODES) esrc[atomicAdd(&cursor[gtid], 1)] = gtid;   // self-loop
}

// ---------------- conv1 GEMM via MFMA: h1 = x @ W1, fused att scores, fp8 packed out ----
__global__ __launch_bounds__(256) void gemm1_kernel(const float* __restrict__ x,
                                                    const uint4* __restrict__ wbf,
                                                    const float* __restrict__ att_src,
                                                    const float* __restrict__ att_dst,
                                                    unsigned int* __restrict__ h1f8,
                                                    float* __restrict__ a_src1,
                                                    float* __restrict__ a_dst1) {
    __shared__ uint4 Xs[1024];   // 64 rows x 16 chunks (swizzled), 16 KB
    __shared__ uint4 Ws[2048];   // 128 cols x 16 chunks (pre-swizzled), 32 KB
    const int t = threadIdx.x;
    const int row0 = blockIdx.x * 64;

    #pragma unroll
    for (int p = 0; p < 8; ++p) Ws[p * 256 + t] = wbf[p * 256 + t];

    #pragma unroll
    for (int p = 0; p < 4; ++p) {
        int cidx = p * 256 + t;
        int row = cidx >> 4, c = cidx & 15;
        int grow = row0 + row;
        float4 xa = make_float4(0.f, 0.f, 0.f, 0.f);
        float4 xb = make_float4(0.f, 0.f, 0.f, 0.f);
        if (grow < N_NODES) {
            xa = *reinterpret_cast<const float4*>(x + (size_t)grow * F_IN + c * 8);
            xb = *reinterpret_cast<const float4*>(x + (size_t)grow * F_IN + c * 8 + 4);
        }
        uint4 u;
        u.x = (unsigned int)f2bf(xa.x) | ((unsigned int)f2bf(xa.y) << 16);
        u.y = (unsigned int)f2bf(xa.z) | ((unsigned int)f2bf(xa.w) << 16);
        u.z = (unsigned int)f2bf(xb.x) | ((unsigned int)f2bf(xb.y) << 16);
        u.w = (unsigned int)f2bf(xb.z) | ((unsigned int)f2bf(xb.w) << 16);
        Xs[row * 16 + (c ^ (row & 15))] = u;
    }
    __syncthreads();

    const int wv = t >> 6;
    const int l  = t & 63;
    const int d  = l & 15;
    const int g  = l >> 4;
    const int arow = wv * 16 + d;

    f32x4 acc[8];
    #pragma unroll
    for (int n = 0; n < 8; ++n) { acc[n][0] = 0.f; acc[n][1] = 0.f; acc[n][2] = 0.f; acc[n][3] = 0.f; }

    #pragma unroll
    for (int ks = 0; ks < 4; ++ks) {
        int kc = ks * 4 + g;
        union { uint4 u; bf16x8 v; } A;
        A.u = Xs[arow * 16 + (kc ^ d)];
        #pragma unroll
        for (int n = 0; n < 8; ++n) {
            union { uint4 u; bf16x8 v; } B;
            B.u = Ws[(n * 16 + d) * 16 + (kc ^ d)];
            acc[n] = __builtin_amdgcn_mfma_f32_16x16x32_bf16(A.v, B.v, acc[n], 0, 0, 0);
        }
    }

    float as8[8], ad8[8];
    #pragma unroll
    for (int n = 0; n < 8; ++n) { as8[n] = att_src[n * 16 + d]; ad8[n] = att_dst[n * 16 + d]; }
    #pragma unroll
    for (int n = 0; n < 8; ++n) {
        #pragma unroll
        for (int r = 0; r < 4; ++r) {
            float ps = acc[n][r] * as8[n];
            float pd = acc[n][r] * ad8[n];
            #pragma unroll
            for (int off = 1; off < 16; off <<= 1) {
                ps += __shfl_xor(ps, off, 16);
                pd += __shfl_xor(pd, off, 16);
            }
            int grow = row0 + wv * 16 + g * 4 + r;
            if (d == 0 && grow < N_NODES) {
                a_src1[grow * 8 + n] = ps;
                a_dst1[grow * 8 + n] = pd;
            }
        }
    }
    // fp8 e4m3 packed store: u32 holds cols [base, base+3], base = n*16 + (d&~3)
    #pragma unroll
    for (int n = 0; n < 8; ++n) {
        #pragma unroll
        for (int r = 0; r < 4; ++r) {
            float v = acc[n][r];
            float v1 = __shfl_xor(v, 1, 64);
            int p01 = __builtin_amdgcn_cvt_pk_fp8_f32(v, v1, 0, false);
            int p23 = __shfl_xor(p01, 2, 64);
            int grow = row0 + wv * 16 + g * 4 + r;
            if (((d & 3) == 0) && grow < N_NODES) {
                unsigned int u = ((unsigned int)p01 & 0xFFFFu) | ((unsigned int)p23 << 16);
                h1f8[(size_t)grow * 32 + n * 4 + (d >> 2)] = u;
            }
        }
    }
}

// ---------------- conv1 aggregation: one wave per dst node, fp8 gather ------------------
__global__ __launch_bounds__(256) void agg1_kernel(const unsigned int* __restrict__ h1f8,
                                                   const float* __restrict__ a_src,
                                                   const float* __restrict__ a_dst,
                                                   const int* __restrict__ rowptr,
                                                   const int* __restrict__ esrc,
                                                   const float* __restrict__ b1,
                                                   float* __restrict__ hout) {
    int wid = (blockIdx.x * 256 + threadIdx.x) >> 6;   // node id (wave-uniform)
    if (wid >= N_NODES) return;
    const int lane = threadIdx.x & 63;
    const int m    = lane & 31;          // dim group: dims 4m..4m+3
    const int half = lane >> 5;          // 0: even edges, 1: odd edges
    const int h    = m >> 2;             // head
    const float ad = a_dst[wid * 8 + h];
    float a0 = 0.f, a1 = 0.f, a2 = 0.f, a3 = 0.f, den = 0.f;
    int j = rowptr[wid];
    const int jend = rowptr[wid + 1];
    for (; j + 8 <= jend; j += 8) {
        int s[4];
        #pragma unroll
        for (int k = 0; k < 4; ++k) s[k] = esrc[j + 2 * k + half];
        unsigned int u[4];
        #pragma unroll
        for (int k = 0; k < 4; ++k) u[k] = h1f8[(size_t)s[k] * 32 + m];
        float e[4];
        #pragma unroll
        for (int k = 0; k < 4; ++k) e[k] = a_src[s[k] * 8 + h];
        #pragma unroll
        for (int k = 0; k < 4; ++k) {
            float p = __expf(lrelu(e[k] + ad));
            den += p;
            f32x2 lo = __builtin_amdgcn_cvt_pk_f32_fp8(u[k], false);
            f32x2 hi = __builtin_amdgcn_cvt_pk_f32_fp8(u[k], true);
            a0 = fmaf(p, lo[0], a0); a1 = fmaf(p, lo[1], a1);
            a2 = fmaf(p, hi[0], a2); a3 = fmaf(p, hi[1], a3);
        }
    }
    for (; j < jend; j += 2) {
        int e_idx = j + half;
        if (e_idx < jend) {
            int s = esrc[e_idx];
            unsigned int u = h1f8[(size_t)s * 32 + m];
            float e = a_src[s * 8 + h];
            float p = __expf(lrelu(e + ad));
            den += p;
            f32x2 lo = __builtin_amdgcn_cvt_pk_f32_fp8(u, false);
            f32x2 hi = __builtin_amdgcn_cvt_pk_f32_fp8(u, true);
            a0 = fmaf(p, lo[0], a0); a1 = fmaf(p, lo[1], a1);
            a2 = fmaf(p, hi[0], a2); a3 = fmaf(p, hi[1], a3);
        }
    }
    a0  += __shfl_xor(a0, 32, 64);
    a1  += __shfl_xor(a1, 32, 64);
    a2  += __shfl_xor(a2, 32, 64);
    a3  += __shfl_xor(a3, 32, 64);
    den += __shfl_xor(den, 32, 64);
    if (half == 0) {
        float inv = 1.f / den;
        float4 bb = *reinterpret_cast<const float4*>(b1 + 4 * m);
        float4 o = make_float4(elu1(a0 * inv + bb.x), elu1(a1 * inv + bb.y),
                               elu1(a2 * inv + bb.z), elu1(a3 * inv + bb.w));
        *reinterpret_cast<float4*>(hout + (size_t)wid * F_IN + 4 * m) = o;
    }
}

// ---------------- conv2 fused: gemm2+att scores (8 subtiles/block) -> barrier -> agg2 ----
__global__ __launch_bounds__(256) void conv2_kernel(const float* __restrict__ h,
                                                    const float* __restrict__ W2,
                                                    const float* __restrict__ att_src2,
                                                    const float* __restrict__ att_dst2,
                                                    const int* __restrict__ rowptr,
                                                    const int* __restrict__ esrc,
                                                    const float* __restrict__ b2,
                                                    float* __restrict__ h2,
                                                    float* __restrict__ a_src2,
                                                    float* __restrict__ a_dst2,
                                                    float* __restrict__ g,
                                                    int* __restrict__ bar) {
    __shared__ float Ws[F_IN * ND2];     // 4 KB
    __shared__ float Hs[32 * 132];       // padded, ~16.9 KB
    const int t = threadIdx.x;
    #pragma unroll
    for (int i = 0; i < 4; ++i) { int idx = i * 256 + t; Ws[idx] = W2[idx]; }

    for (int sub = 0; sub < 8; ++sub) {
        int node0 = (blockIdx.x * 8 + sub) * 32;
        __syncthreads();
        #pragma unroll
        for (int i = 0; i < 4; ++i) {
            int fidx = i * 256 + t;
            int r = fidx >> 5;
            int c4 = fidx & 31;
            int grow = node0 + r;
            float4 v = make_float4(0.f, 0.f, 0.f, 0.f);
            if (grow < N_NODES) v = *reinterpret_cast<const float4*>(h + (size_t)grow * F_IN + c4 * 4);
            *reinterpret_cast<float4*>(&Hs[r * 132 + c4 * 4]) = v;
        }
        __syncthreads();
        int nsub = t >> 3, d = t & 7;
        int node = node0 + nsub;
        float acc = 0.f;
        #pragma unroll 8
        for (int k = 0; k < F_IN; ++k)
            acc = fmaf(Hs[nsub * 132 + k], Ws[k * ND2 + d], acc);
        float vs = acc * att_src2[d];
        float vd = acc * att_dst2[d];
        #pragma unroll
        for (int off = 4; off >= 1; off >>= 1) {
            vs += __shfl_xor(vs, off, 8);
            vd += __shfl_xor(vd, off, 8);
        }
        if (node < N_NODES) {
            h2[node * ND2 + d] = acc;
            if (d == 0) { a_src2[node] = vs; a_dst2[node] = vd; }
        }
    }
    grid_barrier(bar, NBLK);

    // phase 2: agg2, one thread per node (grid covers 50176 >= N_NODES)
    int n = blockIdx.x * 256 + t;
    if (n < N_NODES) {
        float ad = a_dst2[n];
        float acc[8] = {0.f, 0.f, 0.f, 0.f, 0.f, 0.f, 0.f, 0.f};
        float den = 0.f;
        int jend = rowptr[n + 1];
        for (int j = rowptr[n]; j < jend; ++j) {
            int s = esrc[j];
            float p = __expf(lrelu(a_src2[s] + ad));
            den += p;
            float4 va = *reinterpret_cast<const float4*>(h2 + s * ND2);
            float4 vb = *reinterpret_cast<const float4*>(h2 + s * ND2 + 4);
            acc[0] = fmaf(p, va.x, acc[0]); acc[1] = fmaf(p, va.y, acc[1]);
            acc[2] = fmaf(p, va.z, acc[2]); acc[3] = fmaf(p, va.w, acc[3]);
            acc[4] = fmaf(p, vb.x, acc[4]); acc[5] = fmaf(p, vb.y, acc[5]);
            acc[6] = fmaf(p, vb.z, acc[6]); acc[7] = fmaf(p, vb.w, acc[7]);
        }
        float inv = 1.f / den;
        float4 o0 = make_float4(elu1(acc[0] * inv + b2[0]), elu1(acc[1] * inv + b2[1]),
                                elu1(acc[2] * inv + b2[2]), elu1(acc[3] * inv + b2[3]));
        float4 o1 = make_float4(elu1(acc[4] * inv + b2[4]), elu1(acc[5] * inv + b2[5]),
                                elu1(acc[6] * inv + b2[6]), elu1(acc[7] * inv + b2[7]));
        *reinterpret_cast<float4*>(g + n * ND2)     = o0;
        *reinterpret_cast<float4*>(g + n * ND2 + 4) = o1;
    }
}

// ---------------- fc1 stage 1: 1667 blocks x 240 rows, 4-deep float4, no atomics -------
__global__ __launch_bounds__(256) void fc1_stage1(const float* __restrict__ z,
                                                  const float* __restrict__ w,
                                                  float* __restrict__ partial) {
    __shared__ float zs[FC1_RPB];
    __shared__ float4 red[252];
    const int t = threadIdx.x;
    const int b = blockIdx.x;
    const int r0 = b * FC1_RPB;
    if (t < FC1_RPB) {
        int gr = r0 + t;
        zs[t] = (gr < ZLEN) ? z[gr] : 0.f;
    }
    __syncthreads();
    const int c4 = t % 21;
    const int rr = t / 21;
    if (t < 252) {
        float4 a = make_float4(0.f, 0.f, 0.f, 0.f);
        const float4* __restrict__ w4 = reinterpret_cast<const float4*>(w);
        if (r0 + FC1_RPB <= ZLEN) {
            #pragma unroll
            for (int bq = 0; bq < 5; ++bq) {
                float4 wv[4];
                float  zv[4];
                #pragma unroll
                for (int u = 0; u < 4; ++u) {
                    int i = bq * 48 + u * 12 + rr;
                    wv[u] = w4[(size_t)(r0 + i) * 21 + c4];
                    zv[u] = zs[i];
                }
                #pragma unroll
                for (int u = 0; u < 4; ++u) {
                    a.x = fmaf(zv[u], wv[u].x, a.x);
                    a.y = fmaf(zv[u], wv[u].y, a.y);
                    a.z = fmaf(zv[u], wv[u].z, a.z);
                    a.w = fmaf(zv[u], wv[u].w, a.w);
                }
            }
        } else {
            for (int i = rr; i < FC1_RPB; i += 12) {
                if (r0 + i < ZLEN) {
                    float4 wv = w4[(size_t)(r0 + i) * 21 + c4];
                    float  zv = zs[i];
                    a.x = fmaf(zv, wv.x, a.x); a.y = fmaf(zv, wv.y, a.y);
                    a.z = fmaf(zv, wv.z, a.z); a.w = fmaf(zv, wv.w, a.w);
                }
            }
        }
        red[t] = a;
    }
    __syncthreads();
    if (t < 21) {
        float4 s = red[t];
        #pragma unroll
        for (int k = 1; k < 12; ++k) {
            float4 v = red[k * 21 + t];
            s.x += v.x; s.y += v.y; s.z += v.z; s.w += v.w;
        }
        *reinterpret_cast<float4*>(partial + (size_t)b * 88 + t * 4) = s;
    }
}

// ---------------- tail: reduce 1667 partials + MLP + log_softmax ----------------
__global__ __launch_bounds__(1024) void fctail_kernel(const float* __restrict__ partial,
                                                      const float* __restrict__ fc1_b,
                                                      const float* __restrict__ fc2_w,
                                                      const float* __restrict__ fc2_b,
                                                      const float* __restrict__ fc3_w,
                                                      const float* __restrict__ fc3_b,
                                                      float* __restrict__ out) {
    __shared__ float red[1008];
    __shared__ float z1[84];
    __shared__ float z2[24];
    const int t = threadIdx.x;
    if (t < 1008) {
        const int j  = t % 84;
        const int sl = t / 84;          // 0..11
        float s = 0.f;
        for (int b = sl; b < FC1_NB; b += 12)
            s += partial[(size_t)b * 88 + j];
        red[t] = s;
    }
    __syncthreads();
    if (t < 84) {
        float s = 0.f;
        #pragma unroll
        for (int sl = 0; sl < 12; ++sl) s += red[sl * 84 + t];
        z1[t] = elu1(s + fc1_b[t]);
    }
    __syncthreads();
    if (t < 24) {
        float a = fc2_b[t];
        for (int i = 0; i < 84; ++i) a = fmaf(z1[i], fc2_w[i * 24 + t], a);
        z2[t] = elu1(a);
    }
    __syncthreads();
    if (t == 0) {
        float z3[2];
        #pragma unroll
        for (int jj = 0; jj < 2; ++jj) {
            float a = fc3_b[jj];
            for (int i = 0; i < 24; ++i) a = fmaf(z2[i], fc3_w[i * 2 + jj], a);
            z3[jj] = a;
        }
        float m = fmaxf(z3[0], z3[1]);
        float l = m + logf(__expf(z3[0] - m) + __expf(z3[1] - m));
        out[0] = z3[0] - l;
        out[1] = z3[1] - l;
    }
}

extern "C" void kernel_launch(void* const* d_in, const int* in_sizes, int n_in,
                              void* d_out, int out_size, void* d_ws, size_t ws_size,
                              hipStream_t stream) {
    const float* x        = (const float*)d_in[0];
    const int*   ei       = (const int*)d_in[1];
    const float* W1       = (const float*)d_in[2];
    const float* att_src1 = (const float*)d_in[3];
    const float* att_dst1 = (const float*)d_in[4];
    const float* b1       = (const float*)d_in[5];
    const float* W2       = (const float*)d_in[6];
    const float* att_src2 = (const float*)d_in[7];
    const float* att_dst2 = (const float*)d_in[8];
    const float* b2       = (const float*)d_in[9];
    const float* fc1_w    = (const float*)d_in[10];
    const float* fc1_b    = (const float*)d_in[11];
    const float* fc2_w    = (const float*)d_in[12];
    const float* fc2_b    = (const float*)d_in[13];
    const float* fc3_w    = (const float*)d_in[14];
    const float* fc3_b    = (const float*)d_in[15];
    float* out = (float*)d_out;

    char* ws = (char*)d_ws;
    unsigned int* h1f8 = (unsigned int*)(ws + 0);        // 6,400,000 B (fp8 x 128 per node)
    float* hbuf   = (float*)(ws + 6400000);              // 25,600,000 B
    float* a_src1 = (float*)(ws + 32000000);             // 1,600,000 B
    float* a_dst1 = (float*)(ws + 33600000);             // 1,600,000 B
    float* h2     = (float*)(ws + 35200000);             // 1,600,000 B
    float* a_src2 = (float*)(ws + 36800000);             // 200,000 B
    float* a_dst2 = (float*)(ws + 37000000);             // 200,000 B
    float* g      = (float*)(ws + 37200000);             // 1,600,000 B
    int*   counts = (int*)  (ws + 38800000);             // 200,000 B
    int*   rowptr = (int*)  (ws + 39000000);             // 200,064 B
    int*   cursor = (int*)  (ws + 39200064);             // 200,000 B
    int*   esrc   = (int*)  (ws + 39400064);             // 3,400,000 B
    float* partial= (float*)(ws + 42800064);             // 1667*88*4 = 586,784 B
    uint4* wbf    = (uint4*)(ws + 43386848);             // 32,768 B
    int*   bsum   = (int*)  (ws + 43419616);             // 784 B
    int*   bars   = (int*)  (ws + 43420416);             // 8 B (grid-barrier counters)

    prep_kernel<<<NBLK, 256, 0, stream>>>(W1, wbf, counts, bars);
    csr_kernel<<<NBLK, 256, 0, stream>>>(ei, counts, bsum, rowptr, cursor, esrc, &bars[0]);

    gemm1_kernel<<<(N_NODES + 63) / 64, 256, 0, stream>>>(x, wbf, att_src1, att_dst1, h1f8, a_src1, a_dst1);
    agg1_kernel<<<(N_NODES + 3) / 4, 256, 0, stream>>>(h1f8, a_src1, a_dst1, rowptr, esrc, b1, hbuf);

    conv2_kernel<<<NBLK, 256, 0, stream>>>(hbuf, W2, att_src2, att_dst2, rowptr, esrc, b2,
                                           h2, a_src2, a_dst2, g, &bars[1]);

    fc1_stage1<<<FC1_NB, 256, 0, stream>>>(g, fc1_w, partial);
    fctail_kernel<<<1, 1024, 0, stream>>>(partial, fc1_b, fc2_w, fc2_b, fc3_w, fc3_b, out);
}

// Round 12
// 301.464 us; speedup vs baseline: 1.0406x; 1.0406x over previous
//
#include <hip/hip_runtime.h>
#include <math.h>

#define N_NODES 50000
#define F_IN 128
#define NE 800000
#define NH1 8
#define ND1 16
#define ND2 8
#define NEG 0.2f
#define ZLEN (N_NODES * ND2)      // 400000
#define NBLK 196                  // ceil(50000/256); co-resident fused grids
#define FC1_RPB 240
#define FC1_NB 1667               // ceil(400000/240)

typedef __attribute__((ext_vector_type(8))) short bf16x8;   // 8 bf16 (4 VGPRs)
typedef __attribute__((ext_vector_type(4))) float f32x4;
typedef __attribute__((ext_vector_type(2))) float f32x2;

__device__ __forceinline__ float lrelu(float v) { return v > 0.f ? v : NEG * v; }
__device__ __forceinline__ float elu1(float v)  { return v > 0.f ? v : (__expf(v) - 1.f); }

__device__ __forceinline__ unsigned short f2bf(float f) {
    union { float f; unsigned int i; } c; c.f = f;
    unsigned int u = c.i;
    return (unsigned short)((u + 0x7FFFu + ((u >> 16) & 1u)) >> 16);
}
// int64-vs-int32 edge dtype: high words of first 4 entries all zero => int64
__device__ __forceinline__ int ei_is64(const int* __restrict__ ei) {
    return ((ei[1] | ei[3] | ei[5] | ei[7]) == 0) ? 1 : 0;
}

// grid barrier for co-resident grids (grid <= 256 blocks); counter zeroed each call.
__device__ __forceinline__ void grid_barrier(int* cnt, int target) {
    __threadfence();
    __syncthreads();
    if (threadIdx.x == 0) {
        atomicAdd(cnt, 1);
        while (atomicAdd(cnt, 0) < target) __builtin_amdgcn_s_sleep(8);
        __threadfence();   // acquire side
    }
    __syncthreads();
}

// ---------------- CSR build: hist, 4 edges/thread, full-line int4 reads ----------------
__global__ void hist_kernel(const int* __restrict__ ei, int* __restrict__ counts) {
    int t = blockIdx.x * blockDim.x + threadIdx.x;   // handles edges 4t..4t+3
    if (t * 4 >= NE) return;
    int d0, d1, d2, d3;
    if (ei_is64(ei)) {
        const int4* p = reinterpret_cast<const int4*>(ei + 2 * NE);
        int4 a = p[t * 2];
        int4 b = p[t * 2 + 1];
        d0 = a.x; d1 = a.z; d2 = b.x; d3 = b.z;
    } else {
        int4 a = reinterpret_cast<const int4*>(ei + NE)[t];
        d0 = a.x; d1 = a.y; d2 = a.z; d3 = a.w;
    }
    atomicAdd(&counts[d0], 1);
    atomicAdd(&counts[d1], 1);
    atomicAdd(&counts[d2], 1);
    atomicAdd(&counts[d3], 1);
}

// ---------------- scan: single kernel, decoupled lookback (196 blocks co-resident) ------
// v = counts[i] + 1 folds the self-loop; counts only needs zeroing (memset).
__global__ __launch_bounds__(256) void scan_kernel(const int* __restrict__ counts,
                                                   int* __restrict__ bsum,
                                                   int* __restrict__ flag,
                                                   int* __restrict__ rowptr,
                                                   int* __restrict__ cursor) {
    __shared__ int wsum[4];
    __shared__ int wpre[4];
    __shared__ int s_boff;
    const int t = threadIdx.x;
    const int b = blockIdx.x;
    const int lane = t & 63, w = t >> 6;
    const int i = b * 256 + t;
    int v = (i < N_NODES) ? counts[i] + 1 : 0;
    int incl = v;
    #pragma unroll
    for (int off = 1; off < 64; off <<= 1) {
        int u = __shfl_up(incl, off, 64);
        if (lane >= off) incl += u;
    }
    if (lane == 63) wsum[w] = incl;
    __syncthreads();
    if (t == 0) {
        int s = 0;
        #pragma unroll
        for (int j = 0; j < 4; ++j) { wpre[j] = s; s += wsum[j]; }
        bsum[b] = s;
        __threadfence();
        atomicExch(&flag[b], 1);            // publish (release)
    }
    if (t >= 64 && t < 128) {               // wave 1: lookback over predecessors
        int tl = t - 64;
        int s = 0;
        for (int k = tl; k < b; k += 64) {
            while (atomicAdd(&flag[k], 0) == 0) __builtin_amdgcn_s_sleep(2);
            s += atomicAdd(&bsum[k], 0);    // coherent read
        }
        #pragma unroll
        for (int off = 32; off; off >>= 1) s += __shfl_down(s, off, 64);
        if (tl == 0) s_boff = s;
    }
    __syncthreads();
    incl += wpre[w] + s_boff;
    if (i < N_NODES) { rowptr[i + 1] = incl; cursor[i] = incl - v; }
    if (i == 0) rowptr[0] = 0;
}

// fill: 4 edges/thread + self-loop range (full grid)
__global__ void fill_kernel(const int* __restrict__ ei,
                            int* __restrict__ cursor, int* __restrict__ esrc) {
    const int t = blockIdx.x * blockDim.x + threadIdx.x;
    const int NT_E = NE / 4;                      // 200000
    if (t < NT_E) {
        int s0, s1, s2, s3, d0, d1, d2, d3;
        if (ei_is64(ei)) {
            const int4* ps = reinterpret_cast<const int4*>(ei);
            const int4* pd = reinterpret_cast<const int4*>(ei + 2 * NE);
            int4 sa = ps[t * 2], sb = ps[t * 2 + 1];
            int4 da = pd[t * 2], db = pd[t * 2 + 1];
            s0 = sa.x; s1 = sa.z; s2 = sb.x; s3 = sb.z;
            d0 = da.x; d1 = da.z; d2 = db.x; d3 = db.z;
        } else {
            int4 sa = reinterpret_cast<const int4*>(ei)[t];
            int4 da = reinterpret_cast<const int4*>(ei + NE)[t];
            s0 = sa.x; s1 = sa.y; s2 = sa.z; s3 = sa.w;
            d0 = da.x; d1 = da.y; d2 = da.z; d3 = da.w;
        }
        esrc[atomicAdd(&cursor[d0], 1)] = s0;
        esrc[atomicAdd(&cursor[d1], 1)] = s1;
        esrc[atomicAdd(&cursor[d2], 1)] = s2;
        esrc[atomicAdd(&cursor[d3], 1)] = s3;
    } else {
        int i = t - NT_E;
        if (i < N_NODES) esrc[atomicAdd(&cursor[i], 1)] = i;   // self-loop
    }
}

// ---------------- conv1 GEMM via MFMA: h1 = x @ W1, fused att scores, fp8 packed out ----
// W1 converted bf16+swizzled in-kernel during LDS staging (64 KB L2-resident).
__global__ __launch_bounds__(256) void gemm1_kernel(const float* __restrict__ x,
                                                    const float* __restrict__ W1,
                                                    const float* __restrict__ att_src,
                                                    const float* __restrict__ att_dst,
                                                    unsigned int* __restrict__ h1f8,
                                                    float* __restrict__ a_src1,
                                                    float* __restrict__ a_dst1) {
    __shared__ uint4 Xs[1024];   // 64 rows x 16 chunks (swizzled), 16 KB
    __shared__ uint4 Ws[2048];   // 128 cols x 16 chunks (swizzled), 32 KB
    const int t = threadIdx.x;
    const int row0 = blockIdx.x * 64;

    #pragma unroll
    for (int p = 0; p < 8; ++p) {
        int idx = p * 256 + t;
        int col = idx >> 4, kc = idx & 15;
        unsigned int uu[4];
        #pragma unroll
        for (int jj = 0; jj < 4; ++jj) {
            unsigned int lo = f2bf(W1[(kc * 8 + 2 * jj) * 128 + col]);
            unsigned int hi = f2bf(W1[(kc * 8 + 2 * jj + 1) * 128 + col]);
            uu[jj] = lo | (hi << 16);
        }
        uint4 vv; vv.x = uu[0]; vv.y = uu[1]; vv.z = uu[2]; vv.w = uu[3];
        Ws[col * 16 + (kc ^ (col & 15))] = vv;
    }

    #pragma unroll
    for (int p = 0; p < 4; ++p) {
        int cidx = p * 256 + t;
        int row = cidx >> 4, c = cidx & 15;
        int grow = row0 + row;
        float4 xa = make_float4(0.f, 0.f, 0.f, 0.f);
        float4 xb = make_float4(0.f, 0.f, 0.f, 0.f);
        if (grow < N_NODES) {
            xa = *reinterpret_cast<const float4*>(x + (size_t)grow * F_IN + c * 8);
            xb = *reinterpret_cast<const float4*>(x + (size_t)grow * F_IN + c * 8 + 4);
        }
        uint4 u;
        u.x = (unsigned int)f2bf(xa.x) | ((unsigned int)f2bf(xa.y) << 16);
        u.y = (unsigned int)f2bf(xa.z) | ((unsigned int)f2bf(xa.w) << 16);
        u.z = (unsigned int)f2bf(xb.x) | ((unsigned int)f2bf(xb.y) << 16);
        u.w = (unsigned int)f2bf(xb.z) | ((unsigned int)f2bf(xb.w) << 16);
        Xs[row * 16 + (c ^ (row & 15))] = u;
    }
    __syncthreads();

    const int wv = t >> 6;
    const int l  = t & 63;
    const int d  = l & 15;
    const int g  = l >> 4;
    const int arow = wv * 16 + d;

    f32x4 acc[8];
    #pragma unroll
    for (int n = 0; n < 8; ++n) { acc[n][0] = 0.f; acc[n][1] = 0.f; acc[n][2] = 0.f; acc[n][3] = 0.f; }

    #pragma unroll
    for (int ks = 0; ks < 4; ++ks) {
        int kc = ks * 4 + g;
        union { uint4 u; bf16x8 v; } A;
        A.u = Xs[arow * 16 + (kc ^ d)];
        #pragma unroll
        for (int n = 0; n < 8; ++n) {
            union { uint4 u; bf16x8 v; } B;
            B.u = Ws[(n * 16 + d) * 16 + (kc ^ d)];
            acc[n] = __builtin_amdgcn_mfma_f32_16x16x32_bf16(A.v, B.v, acc[n], 0, 0, 0);
        }
    }

    float as8[8], ad8[8];
    #pragma unroll
    for (int n = 0; n < 8; ++n) { as8[n] = att_src[n * 16 + d]; ad8[n] = att_dst[n * 16 + d]; }
    #pragma unroll
    for (int n = 0; n < 8; ++n) {
        #pragma unroll
        for (int r = 0; r < 4; ++r) {
            float ps = acc[n][r] * as8[n];
            float pd = acc[n][r] * ad8[n];
            #pragma unroll
            for (int off = 1; off < 16; off <<= 1) {
                ps += __shfl_xor(ps, off, 16);
                pd += __shfl_xor(pd, off, 16);
            }
            int grow = row0 + wv * 16 + g * 4 + r;
            if (d == 0 && grow < N_NODES) {
                a_src1[grow * 8 + n] = ps;
                a_dst1[grow * 8 + n] = pd;
            }
        }
    }
    // fp8 e4m3 packed store
    #pragma unroll
    for (int n = 0; n < 8; ++n) {
        #pragma unroll
        for (int r = 0; r < 4; ++r) {
            float v = acc[n][r];
            float v1 = __shfl_xor(v, 1, 64);
            int p01 = __builtin_amdgcn_cvt_pk_fp8_f32(v, v1, 0, false);
            int p23 = __shfl_xor(p01, 2, 64);
            int grow = row0 + wv * 16 + g * 4 + r;
            if (((d & 3) == 0) && grow < N_NODES) {
                unsigned int u = ((unsigned int)p01 & 0xFFFFu) | ((unsigned int)p23 << 16);
                h1f8[(size_t)grow * 32 + n * 4 + (d >> 2)] = u;
            }
        }
    }
}

// ---------------- conv1 aggregation: one wave per dst node, fp8 gather ------------------
__global__ __launch_bounds__(256) void agg1_kernel(const unsigned int* __restrict__ h1f8,
                                                   const float* __restrict__ a_src,
                                                   const float* __restrict__ a_dst,
                                                   const int* __restrict__ rowptr,
                                                   const int* __restrict__ esrc,
                                                   const float* __restrict__ b1,
                                                   float* __restrict__ hout) {
    int wid = (blockIdx.x * 256 + threadIdx.x) >> 6;   // node id (wave-uniform)
    if (wid >= N_NODES) return;
    const int lane = threadIdx.x & 63;
    const int m    = lane & 31;          // dim group: dims 4m..4m+3
    const int half = lane >> 5;          // 0: even edges, 1: odd edges
    const int h    = m >> 2;             // head
    const float ad = a_dst[wid * 8 + h];
    float a0 = 0.f, a1 = 0.f, a2 = 0.f, a3 = 0.f, den = 0.f;
    int j = rowptr[wid];
    const int jend = rowptr[wid + 1];
    for (; j + 8 <= jend; j += 8) {
        int s[4];
        #pragma unroll
        for (int k = 0; k < 4; ++k) s[k] = esrc[j + 2 * k + half];
        unsigned int u[4];
        #pragma unroll
        for (int k = 0; k < 4; ++k) u[k] = h1f8[(size_t)s[k] * 32 + m];
        float e[4];
        #pragma unroll
        for (int k = 0; k < 4; ++k) e[k] = a_src[s[k] * 8 + h];
        #pragma unroll
        for (int k = 0; k < 4; ++k) {
            float p = __expf(lrelu(e[k] + ad));
            den += p;
            f32x2 lo = __builtin_amdgcn_cvt_pk_f32_fp8(u[k], false);
            f32x2 hi = __builtin_amdgcn_cvt_pk_f32_fp8(u[k], true);
            a0 = fmaf(p, lo[0], a0); a1 = fmaf(p, lo[1], a1);
            a2 = fmaf(p, hi[0], a2); a3 = fmaf(p, hi[1], a3);
        }
    }
    for (; j < jend; j += 2) {
        int e_idx = j + half;
        if (e_idx < jend) {
            int s = esrc[e_idx];
            unsigned int u = h1f8[(size_t)s * 32 + m];
            float e = a_src[s * 8 + h];
            float p = __expf(lrelu(e + ad));
            den += p;
            f32x2 lo = __builtin_amdgcn_cvt_pk_f32_fp8(u, false);
            f32x2 hi = __builtin_amdgcn_cvt_pk_f32_fp8(u, true);
            a0 = fmaf(p, lo[0], a0); a1 = fmaf(p, lo[1], a1);
            a2 = fmaf(p, hi[0], a2); a3 = fmaf(p, hi[1], a3);
        }
    }
    a0  += __shfl_xor(a0, 32, 64);
    a1  += __shfl_xor(a1, 32, 64);
    a2  += __shfl_xor(a2, 32, 64);
    a3  += __shfl_xor(a3, 32, 64);
    den += __shfl_xor(den, 32, 64);
    if (half == 0) {
        float inv = 1.f / den;
        float4 bb = *reinterpret_cast<const float4*>(b1 + 4 * m);
        float4 o = make_float4(elu1(a0 * inv + bb.x), elu1(a1 * inv + bb.y),
                               elu1(a2 * inv + bb.z), elu1(a3 * inv + bb.w));
        *reinterpret_cast<float4*>(hout + (size_t)wid * F_IN + 4 * m) = o;
    }
}

// ---------------- conv2 fused: gemm2+att scores (8 subtiles/block) -> barrier -> agg2 ----
__global__ __launch_bounds__(256) void conv2_kernel(const float* __restrict__ h,
                                                    const float* __restrict__ W2,
                                                    const float* __restrict__ att_src2,
                                                    const float* __restrict__ att_dst2,
                                                    const int* __restrict__ rowptr,
                                                    const int* __restrict__ esrc,
                                                    const float* __restrict__ b2,
                                                    float* __restrict__ h2,
                                                    float* __restrict__ a_src2,
                                                    float* __restrict__ a_dst2,
                                                    float* __restrict__ g,
                                                    int* __restrict__ bar) {
    __shared__ float Ws[F_IN * ND2];     // 4 KB
    __shared__ float Hs[32 * 132];       // padded, ~16.9 KB
    const int t = threadIdx.x;
    #pragma unroll
    for (int i = 0; i < 4; ++i) { int idx = i * 256 + t; Ws[idx] = W2[idx]; }

    for (int sub = 0; sub < 8; ++sub) {
        int node0 = (blockIdx.x * 8 + sub) * 32;
        __syncthreads();
        #pragma unroll
        for (int i = 0; i < 4; ++i) {
            int fidx = i * 256 + t;
            int r = fidx >> 5;
            int c4 = fidx & 31;
            int grow = node0 + r;
            float4 v = make_float4(0.f, 0.f, 0.f, 0.f);
            if (grow < N_NODES) v = *reinterpret_cast<const float4*>(h + (size_t)grow * F_IN + c4 * 4);
            *reinterpret_cast<float4*>(&Hs[r * 132 + c4 * 4]) = v;
        }
        __syncthreads();
        int nsub = t >> 3, d = t & 7;
        int node = node0 + nsub;
        float acc = 0.f;
        #pragma unroll 8
        for (int k = 0; k < F_IN; ++k)
            acc = fmaf(Hs[nsub * 132 + k], Ws[k * ND2 + d], acc);
        float vs = acc * att_src2[d];
        float vd = acc * att_dst2[d];
        #pragma unroll
        for (int off = 4; off >= 1; off >>= 1) {
            vs += __shfl_xor(vs, off, 8);
            vd += __shfl_xor(vd, off, 8);
        }
        if (node < N_NODES) {
            h2[node * ND2 + d] = acc;
            if (d == 0) { a_src2[node] = vs; a_dst2[node] = vd; }
        }
    }
    grid_barrier(bar, NBLK);

    // phase 2: agg2, one thread per node
    int n = blockIdx.x * 256 + t;
    if (n < N_NODES) {
        float ad = a_dst2[n];
        float acc[8] = {0.f, 0.f, 0.f, 0.f, 0.f, 0.f, 0.f, 0.f};
        float den = 0.f;
        int jend = rowptr[n + 1];
        for (int j = rowptr[n]; j < jend; ++j) {
            int s = esrc[j];
            float p = __expf(lrelu(a_src2[s] + ad));
            den += p;
            float4 va = *reinterpret_cast<const float4*>(h2 + s * ND2);
            float4 vb = *reinterpret_cast<const float4*>(h2 + s * ND2 + 4);
            acc[0] = fmaf(p, va.x, acc[0]); acc[1] = fmaf(p, va.y, acc[1]);
            acc[2] = fmaf(p, va.z, acc[2]); acc[3] = fmaf(p, va.w, acc[3]);
            acc[4] = fmaf(p, vb.x, acc[4]); acc[5] = fmaf(p, vb.y, acc[5]);
            acc[6] = fmaf(p, vb.z, acc[6]); acc[7] = fmaf(p, vb.w, acc[7]);
        }
        float inv = 1.f / den;
        float4 o0 = make_float4(elu1(acc[0] * inv + b2[0]), elu1(acc[1] * inv + b2[1]),
                                elu1(acc[2] * inv + b2[2]), elu1(acc[3] * inv + b2[3]));
        float4 o1 = make_float4(elu1(acc[4] * inv + b2[4]), elu1(acc[5] * inv + b2[5]),
                                elu1(acc[6] * inv + b2[6]), elu1(acc[7] * inv + b2[7]));
        *reinterpret_cast<float4*>(g + n * ND2)     = o0;
        *reinterpret_cast<float4*>(g + n * ND2 + 4) = o1;
    }
}

// ---------------- fc1 stage 1: 1667 blocks x 240 rows, 4-deep float4, no atomics -------
__global__ __launch_bounds__(256) void fc1_stage1(const float* __restrict__ z,
                                                  const float* __restrict__ w,
                                                  float* __restrict__ partial) {
    __shared__ float zs[FC1_RPB];
    __shared__ float4 red[252];
    const int t = threadIdx.x;
    const int b = blockIdx.x;
    const int r0 = b * FC1_RPB;
    if (t < FC1_RPB) {
        int gr = r0 + t;
        zs[t] = (gr < ZLEN) ? z[gr] : 0.f;
    }
    __syncthreads();
    const int c4 = t % 21;
    const int rr = t / 21;
    if (t < 252) {
        float4 a = make_float4(0.f, 0.f, 0.f, 0.f);
        const float4* __restrict__ w4 = reinterpret_cast<const float4*>(w);
        if (r0 + FC1_RPB <= ZLEN) {
            #pragma unroll
            for (int bq = 0; bq < 5; ++bq) {
                float4 wv[4];
                float  zv[4];
                #pragma unroll
                for (int u = 0; u < 4; ++u) {
                    int i = bq * 48 + u * 12 + rr;
                    wv[u] = w4[(size_t)(r0 + i) * 21 + c4];
                    zv[u] = zs[i];
                }
                #pragma unroll
                for (int u = 0; u < 4; ++u) {
                    a.x = fmaf(zv[u], wv[u].x, a.x);
                    a.y = fmaf(zv[u], wv[u].y, a.y);
                    a.z = fmaf(zv[u], wv[u].z, a.z);
                    a.w = fmaf(zv[u], wv[u].w, a.w);
                }
            }
        } else {
            for (int i = rr; i < FC1_RPB; i += 12) {
                if (r0 + i < ZLEN) {
                    float4 wv = w4[(size_t)(r0 + i) * 21 + c4];
                    float  zv = zs[i];
                    a.x = fmaf(zv, wv.x, a.x); a.y = fmaf(zv, wv.y, a.y);
                    a.z = fmaf(zv, wv.z, a.z); a.w = fmaf(zv, wv.w, a.w);
                }
            }
        }
        red[t] = a;
    }
    __syncthreads();
    if (t < 21) {
        float4 s = red[t];
        #pragma unroll
        for (int k = 1; k < 12; ++k) {
            float4 v = red[k * 21 + t];
            s.x += v.x; s.y += v.y; s.z += v.z; s.w += v.w;
        }
        *reinterpret_cast<float4*>(partial + (size_t)b * 88 + t * 4) = s;
    }
}

// ---------------- tail: reduce 1667 partials + MLP + log_softmax ----------------
__global__ __launch_bounds__(1024) void fctail_kernel(const float* __restrict__ partial,
                                                      const float* __restrict__ fc1_b,
                                                      const float* __restrict__ fc2_w,
                                                      const float* __restrict__ fc2_b,
                                                      const float* __restrict__ fc3_w,
                                                      const float* __restrict__ fc3_b,
                                                      float* __restrict__ out) {
    __shared__ float red[1008];
    __shared__ float z1[84];
    __shared__ float z2[24];
    const int t = threadIdx.x;
    if (t < 1008) {
        const int j  = t % 84;
        const int sl = t / 84;          // 0..11
        float s = 0.f;
        for (int b = sl; b < FC1_NB; b += 12)
            s += partial[(size_t)b * 88 + j];
        red[t] = s;
    }
    __syncthreads();
    if (t < 84) {
        float s = 0.f;
        #pragma unroll
        for (int sl = 0; sl < 12; ++sl) s += red[sl * 84 + t];
        z1[t] = elu1(s + fc1_b[t]);
    }
    __syncthreads();
    if (t < 24) {
        float a = fc2_b[t];
        for (int i = 0; i < 84; ++i) a = fmaf(z1[i], fc2_w[i * 24 + t], a);
        z2[t] = elu1(a);
    }
    __syncthreads();
    if (t == 0) {
        float z3[2];
        #pragma unroll
        for (int jj = 0; jj < 2; ++jj) {
            float a = fc3_b[jj];
            for (int i = 0; i < 24; ++i) a = fmaf(z2[i], fc3_w[i * 2 + jj], a);
            z3[jj] = a;
        }
        float m = fmaxf(z3[0], z3[1]);
        float l = m + logf(__expf(z3[0] - m) + __expf(z3[1] - m));
        out[0] = z3[0] - l;
        out[1] = z3[1] - l;
    }
}

extern "C" void kernel_launch(void* const* d_in, const int* in_sizes, int n_in,
                              void* d_out, int out_size, void* d_ws, size_t ws_size,
                              hipStream_t stream) {
    const float* x        = (const float*)d_in[0];
    const int*   ei       = (const int*)d_in[1];
    const float* W1       = (const float*)d_in[2];
    const float* att_src1 = (const float*)d_in[3];
    const float* att_dst1 = (const float*)d_in[4];
    const float* b1       = (const float*)d_in[5];
    const float* W2       = (const float*)d_in[6];
    const float* att_src2 = (const float*)d_in[7];
    const float* att_dst2 = (const float*)d_in[8];
    const float* b2       = (const float*)d_in[9];
    const float* fc1_w    = (const float*)d_in[10];
    const float* fc1_b    = (const float*)d_in[11];
    const float* fc2_w    = (const float*)d_in[12];
    const float* fc2_b    = (const float*)d_in[13];
    const float* fc3_w    = (const float*)d_in[14];
    const float* fc3_b    = (const float*)d_in[15];
    float* out = (float*)d_out;

    char* ws = (char*)d_ws;
    unsigned int* h1f8 = (unsigned int*)(ws + 0);        // 6,400,000 B (fp8 x 128 per node)
    float* hbuf   = (float*)(ws + 6400000);              // 25,600,000 B
    float* a_src1 = (float*)(ws + 32000000);             // 1,600,000 B
    float* a_dst1 = (float*)(ws + 33600000);             // 1,600,000 B
    float* h2     = (float*)(ws + 35200000);             // 1,600,000 B
    float* a_src2 = (float*)(ws + 36800000);             // 200,000 B
    float* a_dst2 = (float*)(ws + 37000000);             // 200,000 B
    float* g      = (float*)(ws + 37200000);             // 1,600,000 B
    int*   counts = (int*)  (ws + 38800000);             // 200,000 B  } zeroed
    int*   flag   = (int*)  (ws + 39000000);             // 784 B      } by one
    int*   bars   = (int*)  (ws + 39000784);             // 16 B       } memset
    int*   rowptr = (int*)  (ws + 39000800);             // 200,064 B
    int*   cursor = (int*)  (ws + 39200864);             // 200,000 B
    int*   esrc   = (int*)  (ws + 39400864);             // 3,400,000 B
    float* partial= (float*)(ws + 42800864);             // 1667*88*4 = 586,784 B
    int*   bsum   = (int*)  (ws + 43387648);             // 784 B

    hipMemsetAsync(counts, 0, 200800, stream);           // counts + flag + bars

    hist_kernel<<<(NE / 4 + 255) / 256, 256, 0, stream>>>(ei, counts);
    scan_kernel<<<NBLK, 256, 0, stream>>>(counts, bsum, flag, rowptr, cursor);
    fill_kernel<<<(NE / 4 + N_NODES + 255) / 256, 256, 0, stream>>>(ei, cursor, esrc);

    gemm1_kernel<<<(N_NODES + 63) / 64, 256, 0, stream>>>(x, W1, att_src1, att_dst1, h1f8, a_src1, a_dst1);
    agg1_kernel<<<(N_NODES + 3) / 4, 256, 0, stream>>>(h1f8, a_src1, a_dst1, rowptr, esrc, b1, hbuf);

    conv2_kernel<<<NBLK, 256, 0, stream>>>(hbuf, W2, att_src2, att_dst2, rowptr, esrc, b2,
                                           h2, a_src2, a_dst2, g, &bars[0]);

    fc1_stage1<<<FC1_NB, 256, 0, stream>>>(g, fc1_w, partial);
    fctail_kernel<<<1, 1024, 0, stream>>>(partial, fc1_b, fc2_w, fc2_b, fc3_w, fc3_b, out);
}

// Round 13
// 280.219 us; speedup vs baseline: 1.1194x; 1.0758x over previous
//
#include <hip/hip_runtime.h>
#include <math.h>

#define N_NODES 50000
#define F_IN 128
#define NE 800000
#define NH1 8
#define ND1 16
#define ND2 8
#define NEG 0.2f
#define ZLEN (N_NODES * ND2)      // 400000
#define NBLK 196                  // ceil(50000/256); co-resident fused grids
#define FC1_RPB 240
#define FC1_NB 1667               // ceil(400000/240)

typedef __attribute__((ext_vector_type(8))) short bf16x8;   // 8 bf16 (4 VGPRs)
typedef __attribute__((ext_vector_type(4))) float f32x4;
typedef __attribute__((ext_vector_type(2))) float f32x2;

__device__ __forceinline__ float lrelu(float v) { return v > 0.f ? v : NEG * v; }
__device__ __forceinline__ float elu1(float v)  { return v > 0.f ? v : (__expf(v) - 1.f); }

__device__ __forceinline__ unsigned short f2bf(float f) {
    union { float f; unsigned int i; } c; c.f = f;
    unsigned int u = c.i;
    return (unsigned short)((u + 0x7FFFu + ((u >> 16) & 1u)) >> 16);
}
// int64-vs-int32 edge dtype: high words of first 4 entries all zero => int64
__device__ __forceinline__ int ei_is64(const int* __restrict__ ei) {
    return ((ei[1] | ei[3] | ei[5] | ei[7]) == 0) ? 1 : 0;
}

// grid barrier for co-resident grids (grid <= 256 blocks); counter zeroed each call.
__device__ __forceinline__ void grid_barrier(int* cnt, int target) {
    __threadfence();
    __syncthreads();
    if (threadIdx.x == 0) {
        atomicAdd(cnt, 1);
        while (atomicAdd(cnt, 0) < target) __builtin_amdgcn_s_sleep(8);
        __threadfence();   // acquire side
    }
    __syncthreads();
}

// ---------------- prep: counts=1 (self-loop), flags/bars=0, W1 -> bf16 swizzled ---------
__global__ __launch_bounds__(256) void prep_kernel(const float* __restrict__ W,
                                                   uint4* __restrict__ wbf,
                                                   int* __restrict__ counts,
                                                   int* __restrict__ flag,
                                                   int* __restrict__ bars) {
    int i = blockIdx.x * 256 + threadIdx.x;
    if (i < N_NODES) counts[i] = 1;   // self-loop folded
    if (i < NBLK) flag[i] = 0;        // scan lookback flags
    if (i < 4) bars[i] = 0;           // grid-barrier counters
    if (i < 2048) {
        int col = i >> 4, kc = i & 15;
        unsigned int u[4];
        #pragma unroll
        for (int jj = 0; jj < 4; ++jj) {
            unsigned int lo = f2bf(W[(kc * 8 + 2 * jj) * 128 + col]);
            unsigned int hi = f2bf(W[(kc * 8 + 2 * jj + 1) * 128 + col]);
            u[jj] = lo | (hi << 16);
        }
        uint4 v; v.x = u[0]; v.y = u[1]; v.z = u[2]; v.w = u[3];
        wbf[col * 16 + (kc ^ (col & 15))] = v;
    }
}

// ---------------- CSR build: hist, 4 edges/thread, full-line int4 reads ----------------
__global__ void hist_kernel(const int* __restrict__ ei, int* __restrict__ counts) {
    int t = blockIdx.x * blockDim.x + threadIdx.x;   // handles edges 4t..4t+3
    if (t * 4 >= NE) return;
    int d0, d1, d2, d3;
    if (ei_is64(ei)) {
        const int4* p = reinterpret_cast<const int4*>(ei + 2 * NE);
        int4 a = p[t * 2];
        int4 b = p[t * 2 + 1];
        d0 = a.x; d1 = a.z; d2 = b.x; d3 = b.z;
    } else {
        int4 a = reinterpret_cast<const int4*>(ei + NE)[t];
        d0 = a.x; d1 = a.y; d2 = a.z; d3 = a.w;
    }
    atomicAdd(&counts[d0], 1);
    atomicAdd(&counts[d1], 1);
    atomicAdd(&counts[d2], 1);
    atomicAdd(&counts[d3], 1);
}

// ---------------- scan: single kernel, decoupled lookback (196 blocks co-resident) ------
__global__ __launch_bounds__(256) void scan_kernel(const int* __restrict__ counts,
                                                   int* __restrict__ bsum,
                                                   int* __restrict__ flag,
                                                   int* __restrict__ rowptr,
                                                   int* __restrict__ cursor) {
    __shared__ int wsum[4];
    __shared__ int wpre[4];
    __shared__ int s_boff;
    const int t = threadIdx.x;
    const int b = blockIdx.x;
    const int lane = t & 63, w = t >> 6;
    const int i = b * 256 + t;
    int v = (i < N_NODES) ? counts[i] : 0;
    int incl = v;
    #pragma unroll
    for (int off = 1; off < 64; off <<= 1) {
        int u = __shfl_up(incl, off, 64);
        if (lane >= off) incl += u;
    }
    if (lane == 63) wsum[w] = incl;
    __syncthreads();
    if (t == 0) {
        int s = 0;
        #pragma unroll
        for (int j = 0; j < 4; ++j) { wpre[j] = s; s += wsum[j]; }
        bsum[b] = s;
        __threadfence();
        atomicExch(&flag[b], 1);            // publish (release)
    }
    if (t >= 64 && t < 128) {               // wave 1: lookback over predecessors
        int tl = t - 64;
        int s = 0;
        for (int k = tl; k < b; k += 64) {
            while (atomicAdd(&flag[k], 0) == 0) __builtin_amdgcn_s_sleep(2);
            s += atomicAdd(&bsum[k], 0);    // coherent read
        }
        #pragma unroll
        for (int off = 32; off; off >>= 1) s += __shfl_down(s, off, 64);
        if (tl == 0) s_boff = s;
    }
    __syncthreads();
    incl += wpre[w] + s_boff;
    if (i < N_NODES) { rowptr[i + 1] = incl; cursor[i] = incl - v; }
    if (i == 0) rowptr[0] = 0;
}

// fill: 4 edges/thread + self-loop range (full grid)
__global__ void fill_kernel(const int* __restrict__ ei,
                            int* __restrict__ cursor, int* __restrict__ esrc) {
    const int t = blockIdx.x * blockDim.x + threadIdx.x;
    const int NT_E = NE / 4;                      // 200000
    if (t < NT_E) {
        int s0, s1, s2, s3, d0, d1, d2, d3;
        if (ei_is64(ei)) {
            const int4* ps = reinterpret_cast<const int4*>(ei);
            const int4* pd = reinterpret_cast<const int4*>(ei + 2 * NE);
            int4 sa = ps[t * 2], sb = ps[t * 2 + 1];
            int4 da = pd[t * 2], db = pd[t * 2 + 1];
            s0 = sa.x; s1 = sa.z; s2 = sb.x; s3 = sb.z;
            d0 = da.x; d1 = da.z; d2 = db.x; d3 = db.z;
        } else {
            int4 sa = reinterpret_cast<const int4*>(ei)[t];
            int4 da = reinterpret_cast<const int4*>(ei + NE)[t];
            s0 = sa.x; s1 = sa.y; s2 = sa.z; s3 = sa.w;
            d0 = da.x; d1 = da.y; d2 = da.z; d3 = da.w;
        }
        esrc[atomicAdd(&cursor[d0], 1)] = s0;
        esrc[atomicAdd(&cursor[d1], 1)] = s1;
        esrc[atomicAdd(&cursor[d2], 1)] = s2;
        esrc[atomicAdd(&cursor[d3], 1)] = s3;
    } else {
        int i = t - NT_E;
        if (i < N_NODES) esrc[atomicAdd(&cursor[i], 1)] = i;   // self-loop
    }
}

// ---------------- conv1 GEMM via MFMA: h1 = x @ W1, fused att scores, fp8 packed out ----
__global__ __launch_bounds__(256) void gemm1_kernel(const float* __restrict__ x,
                                                    const uint4* __restrict__ wbf,
                                                    const float* __restrict__ att_src,
                                                    const float* __restrict__ att_dst,
                                                    unsigned int* __restrict__ h1f8,
                                                    float* __restrict__ a_src1,
                                                    float* __restrict__ a_dst1) {
    __shared__ uint4 Xs[1024];   // 64 rows x 16 chunks (swizzled), 16 KB
    __shared__ uint4 Ws[2048];   // 128 cols x 16 chunks (pre-swizzled), 32 KB
    const int t = threadIdx.x;
    const int row0 = blockIdx.x * 64;

    #pragma unroll
    for (int p = 0; p < 8; ++p) Ws[p * 256 + t] = wbf[p * 256 + t];

    #pragma unroll
    for (int p = 0; p < 4; ++p) {
        int cidx = p * 256 + t;
        int row = cidx >> 4, c = cidx & 15;
        int grow = row0 + row;
        float4 xa = make_float4(0.f, 0.f, 0.f, 0.f);
        float4 xb = make_float4(0.f, 0.f, 0.f, 0.f);
        if (grow < N_NODES) {
            xa = *reinterpret_cast<const float4*>(x + (size_t)grow * F_IN + c * 8);
            xb = *reinterpret_cast<const float4*>(x + (size_t)grow * F_IN + c * 8 + 4);
        }
        uint4 u;
        u.x = (unsigned int)f2bf(xa.x) | ((unsigned int)f2bf(xa.y) << 16);
        u.y = (unsigned int)f2bf(xa.z) | ((unsigned int)f2bf(xa.w) << 16);
        u.z = (unsigned int)f2bf(xb.x) | ((unsigned int)f2bf(xb.y) << 16);
        u.w = (unsigned int)f2bf(xb.z) | ((unsigned int)f2bf(xb.w) << 16);
        Xs[row * 16 + (c ^ (row & 15))] = u;
    }
    __syncthreads();

    const int wv = t >> 6;
    const int l  = t & 63;
    const int d  = l & 15;
    const int g  = l >> 4;
    const int arow = wv * 16 + d;

    f32x4 acc[8];
    #pragma unroll
    for (int n = 0; n < 8; ++n) { acc[n][0] = 0.f; acc[n][1] = 0.f; acc[n][2] = 0.f; acc[n][3] = 0.f; }

    #pragma unroll
    for (int ks = 0; ks < 4; ++ks) {
        int kc = ks * 4 + g;
        union { uint4 u; bf16x8 v; } A;
        A.u = Xs[arow * 16 + (kc ^ d)];
        #pragma unroll
        for (int n = 0; n < 8; ++n) {
            union { uint4 u; bf16x8 v; } B;
            B.u = Ws[(n * 16 + d) * 16 + (kc ^ d)];
            acc[n] = __builtin_amdgcn_mfma_f32_16x16x32_bf16(A.v, B.v, acc[n], 0, 0, 0);
        }
    }

    float as8[8], ad8[8];
    #pragma unroll
    for (int n = 0; n < 8; ++n) { as8[n] = att_src[n * 16 + d]; ad8[n] = att_dst[n * 16 + d]; }
    #pragma unroll
    for (int n = 0; n < 8; ++n) {
        #pragma unroll
        for (int r = 0; r < 4; ++r) {
            float ps = acc[n][r] * as8[n];
            float pd = acc[n][r] * ad8[n];
            #pragma unroll
            for (int off = 1; off < 16; off <<= 1) {
                ps += __shfl_xor(ps, off, 16);
                pd += __shfl_xor(pd, off, 16);
            }
            int grow = row0 + wv * 16 + g * 4 + r;
            if (d == 0 && grow < N_NODES) {
                a_src1[grow * 8 + n] = ps;
                a_dst1[grow * 8 + n] = pd;
            }
        }
    }
    // fp8 e4m3 packed store
    #pragma unroll
    for (int n = 0; n < 8; ++n) {
        #pragma unroll
        for (int r = 0; r < 4; ++r) {
            float v = acc[n][r];
            float v1 = __shfl_xor(v, 1, 64);
            int p01 = __builtin_amdgcn_cvt_pk_fp8_f32(v, v1, 0, false);
            int p23 = __shfl_xor(p01, 2, 64);
            int grow = row0 + wv * 16 + g * 4 + r;
            if (((d & 3) == 0) && grow < N_NODES) {
                unsigned int u = ((unsigned int)p01 & 0xFFFFu) | ((unsigned int)p23 << 16);
                h1f8[(size_t)grow * 32 + n * 4 + (d >> 2)] = u;
            }
        }
    }
}

// ---------------- conv1 aggregation: one wave per dst node, fp8 gather ------------------
__global__ __launch_bounds__(256) void agg1_kernel(const unsigned int* __restrict__ h1f8,
                                                   const float* __restrict__ a_src,
                                                   const float* __restrict__ a_dst,
                                                   const int* __restrict__ rowptr,
                                                   const int* __restrict__ esrc,
                                                   const float* __restrict__ b1,
                                                   float* __restrict__ hout) {
    int wid = (blockIdx.x * 256 + threadIdx.x) >> 6;   // node id (wave-uniform)
    if (wid >= N_NODES) return;
    const int lane = threadIdx.x & 63;
    const int m    = lane & 31;          // dim group: dims 4m..4m+3
    const int half = lane >> 5;          // 0: even edges, 1: odd edges
    const int h    = m >> 2;             // head
    const float ad = a_dst[wid * 8 + h];
    float a0 = 0.f, a1 = 0.f, a2 = 0.f, a3 = 0.f, den = 0.f;
    int j = rowptr[wid];
    const int jend = rowptr[wid + 1];
    for (; j + 8 <= jend; j += 8) {
        int s[4];
        #pragma unroll
        for (int k = 0; k < 4; ++k) s[k] = esrc[j + 2 * k + half];
        unsigned int u[4];
        #pragma unroll
        for (int k = 0; k < 4; ++k) u[k] = h1f8[(size_t)s[k] * 32 + m];
        float e[4];
        #pragma unroll
        for (int k = 0; k < 4; ++k) e[k] = a_src[s[k] * 8 + h];
        #pragma unroll
        for (int k = 0; k < 4; ++k) {
            float p = __expf(lrelu(e[k] + ad));
            den += p;
            f32x2 lo = __builtin_amdgcn_cvt_pk_f32_fp8(u[k], false);
            f32x2 hi = __builtin_amdgcn_cvt_pk_f32_fp8(u[k], true);
            a0 = fmaf(p, lo[0], a0); a1 = fmaf(p, lo[1], a1);
            a2 = fmaf(p, hi[0], a2); a3 = fmaf(p, hi[1], a3);
        }
    }
    for (; j < jend; j += 2) {
        int e_idx = j + half;
        if (e_idx < jend) {
            int s = esrc[e_idx];
            unsigned int u = h1f8[(size_t)s * 32 + m];
            float e = a_src[s * 8 + h];
            float p = __expf(lrelu(e + ad));
            den += p;
            f32x2 lo = __builtin_amdgcn_cvt_pk_f32_fp8(u, false);
            f32x2 hi = __builtin_amdgcn_cvt_pk_f32_fp8(u, true);
            a0 = fmaf(p, lo[0], a0); a1 = fmaf(p, lo[1], a1);
            a2 = fmaf(p, hi[0], a2); a3 = fmaf(p, hi[1], a3);
        }
    }
    a0  += __shfl_xor(a0, 32, 64);
    a1  += __shfl_xor(a1, 32, 64);
    a2  += __shfl_xor(a2, 32, 64);
    a3  += __shfl_xor(a3, 32, 64);
    den += __shfl_xor(den, 32, 64);
    if (half == 0) {
        float inv = 1.f / den;
        float4 bb = *reinterpret_cast<const float4*>(b1 + 4 * m);
        float4 o = make_float4(elu1(a0 * inv + bb.x), elu1(a1 * inv + bb.y),
                               elu1(a2 * inv + bb.z), elu1(a3 * inv + bb.w));
        *reinterpret_cast<float4*>(hout + (size_t)wid * F_IN + 4 * m) = o;
    }
}

// ---------------- conv2 fused: gemm2+att scores (8 subtiles/block) -> barrier -> agg2 ----
__global__ __launch_bounds__(256) void conv2_kernel(const float* __restrict__ h,
                                                    const float* __restrict__ W2,
                                                    const float* __restrict__ att_src2,
                                                    const float* __restrict__ att_dst2,
                                                    const int* __restrict__ rowptr,
                                                    const int* __restrict__ esrc,
                                                    const float* __restrict__ b2,
                                                    float* __restrict__ h2,
                                                    float* __restrict__ a_src2,
                                                    float* __restrict__ a_dst2,
                                                    float* __restrict__ g,
                                                    int* __restrict__ bar) {
    __shared__ float Ws[F_IN * ND2];     // 4 KB
    __shared__ float Hs[32 * 132];       // padded, ~16.9 KB
    const int t = threadIdx.x;
    #pragma unroll
    for (int i = 0; i < 4; ++i) { int idx = i * 256 + t; Ws[idx] = W2[idx]; }

    for (int sub = 0; sub < 8; ++sub) {
        int node0 = (blockIdx.x * 8 + sub) * 32;
        __syncthreads();
        #pragma unroll
        for (int i = 0; i < 4; ++i) {
            int fidx = i * 256 + t;
            int r = fidx >> 5;
            int c4 = fidx & 31;
            int grow = node0 + r;
            float4 v = make_float4(0.f, 0.f, 0.f, 0.f);
            if (grow < N_NODES) v = *reinterpret_cast<const float4*>(h + (size_t)grow * F_IN + c4 * 4);
            *reinterpret_cast<float4*>(&Hs[r * 132 + c4 * 4]) = v;
        }
        __syncthreads();
        int nsub = t >> 3, d = t & 7;
        int node = node0 + nsub;
        float acc = 0.f;
        #pragma unroll 8
        for (int k = 0; k < F_IN; ++k)
            acc = fmaf(Hs[nsub * 132 + k], Ws[k * ND2 + d], acc);
        float vs = acc * att_src2[d];
        float vd = acc * att_dst2[d];
        #pragma unroll
        for (int off = 4; off >= 1; off >>= 1) {
            vs += __shfl_xor(vs, off, 8);
            vd += __shfl_xor(vd, off, 8);
        }
        if (node < N_NODES) {
            h2[node * ND2 + d] = acc;
            if (d == 0) { a_src2[node] = vs; a_dst2[node] = vd; }
        }
    }
    grid_barrier(bar, NBLK);

    // phase 2: agg2, one thread per node
    int n = blockIdx.x * 256 + t;
    if (n < N_NODES) {
        float ad = a_dst2[n];
        float acc[8] = {0.f, 0.f, 0.f, 0.f, 0.f, 0.f, 0.f, 0.f};
        float den = 0.f;
        int jend = rowptr[n + 1];
        for (int j = rowptr[n]; j < jend; ++j) {
            int s = esrc[j];
            float p = __expf(lrelu(a_src2[s] + ad));
            den += p;
            float4 va = *reinterpret_cast<const float4*>(h2 + s * ND2);
            float4 vb = *reinterpret_cast<const float4*>(h2 + s * ND2 + 4);
            acc[0] = fmaf(p, va.x, acc[0]); acc[1] = fmaf(p, va.y, acc[1]);
            acc[2] = fmaf(p, va.z, acc[2]); acc[3] = fmaf(p, va.w, acc[3]);
            acc[4] = fmaf(p, vb.x, acc[4]); acc[5] = fmaf(p, vb.y, acc[5]);
            acc[6] = fmaf(p, vb.z, acc[6]); acc[7] = fmaf(p, vb.w, acc[7]);
        }
        float inv = 1.f / den;
        float4 o0 = make_float4(elu1(acc[0] * inv + b2[0]), elu1(acc[1] * inv + b2[1]),
                                elu1(acc[2] * inv + b2[2]), elu1(acc[3] * inv + b2[3]));
        float4 o1 = make_float4(elu1(acc[4] * inv + b2[4]), elu1(acc[5] * inv + b2[5]),
                                elu1(acc[6] * inv + b2[6]), elu1(acc[7] * inv + b2[7]));
        *reinterpret_cast<float4*>(g + n * ND2)     = o0;
        *reinterpret_cast<float4*>(g + n * ND2 + 4) = o1;
    }
}

// ---------------- fc1 stage 1: 1667 blocks x 240 rows, 4-deep float4, no atomics -------
__global__ __launch_bounds__(256) void fc1_stage1(const float* __restrict__ z,
                                                  const float* __restrict__ w,
                                                  float* __restrict__ partial) {
    __shared__ float zs[FC1_RPB];
    __shared__ float4 red[252];
    const int t = threadIdx.x;
    const int b = blockIdx.x;
    const int r0 = b * FC1_RPB;
    if (t < FC1_RPB) {
        int gr = r0 + t;
        zs[t] = (gr < ZLEN) ? z[gr] : 0.f;
    }
    __syncthreads();
    const int c4 = t % 21;
    const int rr = t / 21;
    if (t < 252) {
        float4 a = make_float4(0.f, 0.f, 0.f, 0.f);
        const float4* __restrict__ w4 = reinterpret_cast<const float4*>(w);
        if (r0 + FC1_RPB <= ZLEN) {
            #pragma unroll
            for (int bq = 0; bq < 5; ++bq) {
                float4 wv[4];
                float  zv[4];
                #pragma unroll
                for (int u = 0; u < 4; ++u) {
                    int i = bq * 48 + u * 12 + rr;
                    wv[u] = w4[(size_t)(r0 + i) * 21 + c4];
                    zv[u] = zs[i];
                }
                #pragma unroll
                for (int u = 0; u < 4; ++u) {
                    a.x = fmaf(zv[u], wv[u].x, a.x);
                    a.y = fmaf(zv[u], wv[u].y, a.y);
                    a.z = fmaf(zv[u], wv[u].z, a.z);
                    a.w = fmaf(zv[u], wv[u].w, a.w);
                }
            }
        } else {
            for (int i = rr; i < FC1_RPB; i += 12) {
                if (r0 + i < ZLEN) {
                    float4 wv = w4[(size_t)(r0 + i) * 21 + c4];
                    float  zv = zs[i];
                    a.x = fmaf(zv, wv.x, a.x); a.y = fmaf(zv, wv.y, a.y);
                    a.z = fmaf(zv, wv.z, a.z); a.w = fmaf(zv, wv.w, a.w);
                }
            }
        }
        red[t] = a;
    }
    __syncthreads();
    if (t < 21) {
        float4 s = red[t];
        #pragma unroll
        for (int k = 1; k < 12; ++k) {
            float4 v = red[k * 21 + t];
            s.x += v.x; s.y += v.y; s.z += v.z; s.w += v.w;
        }
        *reinterpret_cast<float4*>(partial + (size_t)b * 88 + t * 4) = s;
    }
}

// ---------------- tail: reduce 1667 partials + MLP + log_softmax ----------------
__global__ __launch_bounds__(1024) void fctail_kernel(const float* __restrict__ partial,
                                                      const float* __restrict__ fc1_b,
                                                      const float* __restrict__ fc2_w,
                                                      const float* __restrict__ fc2_b,
                                                      const float* __restrict__ fc3_w,
                                                      const float* __restrict__ fc3_b,
                                                      float* __restrict__ out) {
    __shared__ float red[1008];
    __shared__ float z1[84];
    __shared__ float z2[24];
    const int t = threadIdx.x;
    if (t < 1008) {
        const int j  = t % 84;
        const int sl = t / 84;          // 0..11
        float s = 0.f;
        for (int b = sl; b < FC1_NB; b += 12)
            s += partial[(size_t)b * 88 + j];
        red[t] = s;
    }
    __syncthreads();
    if (t < 84) {
        float s = 0.f;
        #pragma unroll
        for (int sl = 0; sl < 12; ++sl) s += red[sl * 84 + t];
        z1[t] = elu1(s + fc1_b[t]);
    }
    __syncthreads();
    if (t < 24) {
        float a = fc2_b[t];
        for (int i = 0; i < 84; ++i) a = fmaf(z1[i], fc2_w[i * 24 + t], a);
        z2[t] = elu1(a);
    }
    __syncthreads();
    if (t == 0) {
        float z3[2];
        #pragma unroll
        for (int jj = 0; jj < 2; ++jj) {
            float a = fc3_b[jj];
            for (int i = 0; i < 24; ++i) a = fmaf(z2[i], fc3_w[i * 2 + jj], a);
            z3[jj] = a;
        }
        float m = fmaxf(z3[0], z3[1]);
        float l = m + logf(__expf(z3[0] - m) + __expf(z3[1] - m));
        out[0] = z3[0] - l;
        out[1] = z3[1] - l;
    }
}

extern "C" void kernel_launch(void* const* d_in, const int* in_sizes, int n_in,
                              void* d_out, int out_size, void* d_ws, size_t ws_size,
                              hipStream_t stream) {
    const float* x        = (const float*)d_in[0];
    const int*   ei       = (const int*)d_in[1];
    const float* W1       = (const float*)d_in[2];
    const float* att_src1 = (const float*)d_in[3];
    const float* att_dst1 = (const float*)d_in[4];
    const float* b1       = (const float*)d_in[5];
    const float* W2       = (const float*)d_in[6];
    const float* att_src2 = (const float*)d_in[7];
    const float* att_dst2 = (const float*)d_in[8];
    const float* b2       = (const float*)d_in[9];
    const float* fc1_w    = (const float*)d_in[10];
    const float* fc1_b    = (const float*)d_in[11];
    const float* fc2_w    = (const float*)d_in[12];
    const float* fc2_b    = (const float*)d_in[13];
    const float* fc3_w    = (const float*)d_in[14];
    const float* fc3_b    = (const float*)d_in[15];
    float* out = (float*)d_out;

    char* ws = (char*)d_ws;
    unsigned int* h1f8 = (unsigned int*)(ws + 0);        // 6,400,000 B (fp8 x 128 per node)
    float* hbuf   = (float*)(ws + 6400000);              // 25,600,000 B
    float* a_src1 = (float*)(ws + 32000000);             // 1,600,000 B
    float* a_dst1 = (float*)(ws + 33600000);             // 1,600,000 B
    float* h2     = (float*)(ws + 35200000);             // 1,600,000 B
    float* a_src2 = (float*)(ws + 36800000);             // 200,000 B
    float* a_dst2 = (float*)(ws + 37000000);             // 200,000 B
    float* g      = (float*)(ws + 37200000);             // 1,600,000 B
    int*   counts = (int*)  (ws + 38800000);             // 200,000 B
    int*   flag   = (int*)  (ws + 39000000);             // 784 B
    int*   bars   = (int*)  (ws + 39000784);             // 16 B
    int*   rowptr = (int*)  (ws + 39000800);             // 200,064 B
    int*   cursor = (int*)  (ws + 39200864);             // 200,000 B
    int*   esrc   = (int*)  (ws + 39400864);             // 3,400,000 B
    float* partial= (float*)(ws + 42800864);             // 1667*88*4 = 586,784 B
    int*   bsum   = (int*)  (ws + 43387648);             // 784 B
    uint4* wbf    = (uint4*)(ws + 43388448);             // 32,768 B

    prep_kernel<<<NBLK, 256, 0, stream>>>(W1, wbf, counts, flag, bars);
    hist_kernel<<<(NE / 4 + 255) / 256, 256, 0, stream>>>(ei, counts);
    scan_kernel<<<NBLK, 256, 0, stream>>>(counts, bsum, flag, rowptr, cursor);
    fill_kernel<<<(NE / 4 + N_NODES + 255) / 256, 256, 0, stream>>>(ei, cursor, esrc);

    gemm1_kernel<<<(N_NODES + 63) / 64, 256, 0, stream>>>(x, wbf, att_src1, att_dst1, h1f8, a_src1, a_dst1);
    agg1_kernel<<<(N_NODES + 3) / 4, 256, 0, stream>>>(h1f8, a_src1, a_dst1, rowptr, esrc, b1, hbuf);

    conv2_kernel<<<NBLK, 256, 0, stream>>>(hbuf, W2, att_src2, att_dst2, rowptr, esrc, b2,
                                           h2, a_src2, a_dst2, g, &bars[0]);

    fc1_stage1<<<FC1_NB, 256, 0, stream>>>(g, fc1_w, partial);
    fctail_kernel<<<1, 1024, 0, stream>>>(partial, fc1_b, fc2_w, fc2_b, fc3_w, fc3_b, out);
}

// Round 14
// 237.060 us; speedup vs baseline: 1.3232x; 1.1821x over previous
//
#include <hip/hip_runtime.h>
#include <math.h>

#define N_NODES 50000
#define F_IN 128
#define NE 800000
#define NH1 8
#define ND1 16
#define ND2 8
#define NEG 0.2f
#define ZLEN (N_NODES * ND2)      // 400000
#define NBLK 196                  // ceil(50000/256)
#define FC1_RPB 240
#define FC1_NB 1667               // ceil(400000/240)

typedef __attribute__((ext_vector_type(8))) short bf16x8;   // 8 bf16 (4 VGPRs)
typedef __attribute__((ext_vector_type(4))) float f32x4;
typedef __attribute__((ext_vector_type(2))) float f32x2;

__device__ __forceinline__ float lrelu(float v) { return v > 0.f ? v : NEG * v; }
__device__ __forceinline__ float elu1(float v)  { return v > 0.f ? v : (__expf(v) - 1.f); }

__device__ __forceinline__ unsigned short f2bf(float f) {
    union { float f; unsigned int i; } c; c.f = f;
    unsigned int u = c.i;
    return (unsigned short)((u + 0x7FFFu + ((u >> 16) & 1u)) >> 16);
}
// int64-vs-int32 edge dtype: high words of first 4 entries all zero => int64
__device__ __forceinline__ int ei_is64(const int* __restrict__ ei) {
    return ((ei[1] | ei[3] | ei[5] | ei[7]) == 0) ? 1 : 0;
}

// ---------------- prep: W1 -> bf16 swizzled + counts init (fused) ----------------
__global__ __launch_bounds__(256) void prep_kernel(const float* __restrict__ W,
                                                   uint4* __restrict__ wbf,
                                                   int* __restrict__ counts) {
    int i = blockIdx.x * 256 + threadIdx.x;
    if (i < N_NODES) counts[i] = 1;   // self-loop folded
    if (i < 2048) {
        int col = i >> 4, kc = i & 15;
        unsigned int u[4];
        #pragma unroll
        for (int jj = 0; jj < 4; ++jj) {
            unsigned int lo = f2bf(W[(kc * 8 + 2 * jj) * 128 + col]);
            unsigned int hi = f2bf(W[(kc * 8 + 2 * jj + 1) * 128 + col]);
            u[jj] = lo | (hi << 16);
        }
        uint4 v; v.x = u[0]; v.y = u[1]; v.z = u[2]; v.w = u[3];
        wbf[col * 16 + (kc ^ (col & 15))] = v;
    }
}

// ---------------- CSR build: hist, 4 edges/thread, full-line int4 reads ----------------
__global__ void hist_kernel(const int* __restrict__ ei, int* __restrict__ counts) {
    int t = blockIdx.x * blockDim.x + threadIdx.x;   // handles edges 4t..4t+3
    if (t * 4 >= NE) return;
    int d0, d1, d2, d3;
    if (ei_is64(ei)) {
        const int4* p = reinterpret_cast<const int4*>(ei + 2 * NE);
        int4 a = p[t * 2];
        int4 b = p[t * 2 + 1];
        d0 = a.x; d1 = a.z; d2 = b.x; d3 = b.z;
    } else {
        int4 a = reinterpret_cast<const int4*>(ei + NE)[t];
        d0 = a.x; d1 = a.y; d2 = a.z; d3 = a.w;
    }
    atomicAdd(&counts[d0], 1);
    atomicAdd(&counts[d1], 1);
    atomicAdd(&counts[d2], 1);
    atomicAdd(&counts[d3], 1);
}

// scan stage 1: per-block sums
__global__ __launch_bounds__(256) void scan1_kernel(const int* __restrict__ counts,
                                                    int* __restrict__ bsum) {
    const int t = threadIdx.x;
    int i = blockIdx.x * 256 + t;
    int v = (i < N_NODES) ? counts[i] : 0;
    #pragma unroll
    for (int off = 32; off; off >>= 1) v += __shfl_down(v, off, 64);
    __shared__ int ws[4];
    if ((t & 63) == 0) ws[t >> 6] = v;
    __syncthreads();
    if (t == 0) bsum[blockIdx.x] = ws[0] + ws[1] + ws[2] + ws[3];
}

// scan stage 2: each block derives its own offset from bsum
__global__ __launch_bounds__(256) void scan3_kernel(const int* __restrict__ counts,
                                                    const int* __restrict__ bsum,
                                                    int* __restrict__ rowptr,
                                                    int* __restrict__ cursor) {
    __shared__ int wsum[4];
    __shared__ int wpre[4];
    __shared__ int s_boff;
    const int t = threadIdx.x;
    const int lane = t & 63, w = t >> 6;
    int i = blockIdx.x * 256 + t;
    int v = (i < N_NODES) ? counts[i] : 0;
    int incl = v;
    #pragma unroll
    for (int off = 1; off < 64; off <<= 1) {
        int u = __shfl_up(incl, off, 64);
        if (lane >= off) incl += u;
    }
    if (lane == 63) wsum[w] = incl;
    if (t < 64) {
        int s = 0;
        for (int k = t; k < blockIdx.x; k += 64) s += bsum[k];
        #pragma unroll
        for (int off = 32; off; off >>= 1) s += __shfl_down(s, off, 64);
        if (t == 0) s_boff = s;
    }
    __syncthreads();
    if (t == 0) { int s = 0; for (int j = 0; j < 4; ++j) { wpre[j] = s; s += wsum[j]; } }
    __syncthreads();
    incl += wpre[w] + s_boff;
    if (i < N_NODES) { rowptr[i + 1] = incl; cursor[i] = incl - v; }
    if (i == 0) rowptr[0] = 0;
}

// fill: 4 edges/thread + self-loop range
__global__ void fill_kernel(const int* __restrict__ ei,
                            int* __restrict__ cursor, int* __restrict__ esrc) {
    const int t = blockIdx.x * blockDim.x + threadIdx.x;
    const int NT_E = NE / 4;                      // 200000
    if (t < NT_E) {
        int s0, s1, s2, s3, d0, d1, d2, d3;
        if (ei_is64(ei)) {
            const int4* ps = reinterpret_cast<const int4*>(ei);
            const int4* pd = reinterpret_cast<const int4*>(ei + 2 * NE);
            int4 sa = ps[t * 2], sb = ps[t * 2 + 1];
            int4 da = pd[t * 2], db = pd[t * 2 + 1];
            s0 = sa.x; s1 = sa.z; s2 = sb.x; s3 = sb.z;
            d0 = da.x; d1 = da.z; d2 = db.x; d3 = db.z;
        } else {
            int4 sa = reinterpret_cast<const int4*>(ei)[t];
            int4 da = reinterpret_cast<const int4*>(ei + NE)[t];
            s0 = sa.x; s1 = sa.y; s2 = sa.z; s3 = sa.w;
            d0 = da.x; d1 = da.y; d2 = da.z; d3 = da.w;
        }
        esrc[atomicAdd(&cursor[d0], 1)] = s0;
        esrc[atomicAdd(&cursor[d1], 1)] = s1;
        esrc[atomicAdd(&cursor[d2], 1)] = s2;
        esrc[atomicAdd(&cursor[d3], 1)] = s3;
    } else {
        int i = t - NT_E;
        if (i < N_NODES) esrc[atomicAdd(&cursor[i], 1)] = i;   // self-loop
    }
}

// ---------------- conv1 GEMM via MFMA: h1 = x @ W1, fused att scores, fp8 packed out ----
__global__ __launch_bounds__(256) void gemm1_kernel(const float* __restrict__ x,
                                                    const uint4* __restrict__ wbf,
                                                    const float* __restrict__ att_src,
                                                    const float* __restrict__ att_dst,
                                                    unsigned int* __restrict__ h1f8,
                                                    float* __restrict__ a_src1,
                                                    float* __restrict__ a_dst1) {
    __shared__ uint4 Xs[1024];   // 64 rows x 16 chunks (swizzled), 16 KB
    __shared__ uint4 Ws[2048];   // 128 cols x 16 chunks (pre-swizzled), 32 KB
    const int t = threadIdx.x;
    const int row0 = blockIdx.x * 64;

    #pragma unroll
    for (int p = 0; p < 8; ++p) Ws[p * 256 + t] = wbf[p * 256 + t];

    #pragma unroll
    for (int p = 0; p < 4; ++p) {
        int cidx = p * 256 + t;
        int row = cidx >> 4, c = cidx & 15;
        int grow = row0 + row;
        float4 xa = make_float4(0.f, 0.f, 0.f, 0.f);
        float4 xb = make_float4(0.f, 0.f, 0.f, 0.f);
        if (grow < N_NODES) {
            xa = *reinterpret_cast<const float4*>(x + (size_t)grow * F_IN + c * 8);
            xb = *reinterpret_cast<const float4*>(x + (size_t)grow * F_IN + c * 8 + 4);
        }
        uint4 u;
        u.x = (unsigned int)f2bf(xa.x) | ((unsigned int)f2bf(xa.y) << 16);
        u.y = (unsigned int)f2bf(xa.z) | ((unsigned int)f2bf(xa.w) << 16);
        u.z = (unsigned int)f2bf(xb.x) | ((unsigned int)f2bf(xb.y) << 16);
        u.w = (unsigned int)f2bf(xb.z) | ((unsigned int)f2bf(xb.w) << 16);
        Xs[row * 16 + (c ^ (row & 15))] = u;
    }
    __syncthreads();

    const int wv = t >> 6;
    const int l  = t & 63;
    const int d  = l & 15;
    const int g  = l >> 4;
    const int arow = wv * 16 + d;

    f32x4 acc[8];
    #pragma unroll
    for (int n = 0; n < 8; ++n) { acc[n][0] = 0.f; acc[n][1] = 0.f; acc[n][2] = 0.f; acc[n][3] = 0.f; }

    #pragma unroll
    for (int ks = 0; ks < 4; ++ks) {
        int kc = ks * 4 + g;
        union { uint4 u; bf16x8 v; } A;
        A.u = Xs[arow * 16 + (kc ^ d)];
        #pragma unroll
        for (int n = 0; n < 8; ++n) {
            union { uint4 u; bf16x8 v; } B;
            B.u = Ws[(n * 16 + d) * 16 + (kc ^ d)];
            acc[n] = __builtin_amdgcn_mfma_f32_16x16x32_bf16(A.v, B.v, acc[n], 0, 0, 0);
        }
    }

    float as8[8], ad8[8];
    #pragma unroll
    for (int n = 0; n < 8; ++n) { as8[n] = att_src[n * 16 + d]; ad8[n] = att_dst[n * 16 + d]; }
    #pragma unroll
    for (int n = 0; n < 8; ++n) {
        #pragma unroll
        for (int r = 0; r < 4; ++r) {
            float ps = acc[n][r] * as8[n];
            float pd = acc[n][r] * ad8[n];
            #pragma unroll
            for (int off = 1; off < 16; off <<= 1) {
                ps += __shfl_xor(ps, off, 16);
                pd += __shfl_xor(pd, off, 16);
            }
            int grow = row0 + wv * 16 + g * 4 + r;
            if (d == 0 && grow < N_NODES) {
                a_src1[grow * 8 + n] = ps;
                a_dst1[grow * 8 + n] = pd;
            }
        }
    }
    // fp8 e4m3 packed store
    #pragma unroll
    for (int n = 0; n < 8; ++n) {
        #pragma unroll
        for (int r = 0; r < 4; ++r) {
            float v = acc[n][r];
            float v1 = __shfl_xor(v, 1, 64);
            int p01 = __builtin_amdgcn_cvt_pk_fp8_f32(v, v1, 0, false);
            int p23 = __shfl_xor(p01, 2, 64);
            int grow = row0 + wv * 16 + g * 4 + r;
            if (((d & 3) == 0) && grow < N_NODES) {
                unsigned int u = ((unsigned int)p01 & 0xFFFFu) | ((unsigned int)p23 << 16);
                h1f8[(size_t)grow * 32 + n * 4 + (d >> 2)] = u;
            }
        }
    }
}

// ---------------- conv1 aggregation: one wave per dst node, fp8 uint2 gather ------------
// Quarter-wave edge groups: 16 lanes/edge (lane m = lane&15 covers dims 8m..8m+7),
// 4 edge groups (gq = lane>>4), 2x unrolled => 8 edges in flight per wave.
// Merge via reduce-scatter butterfly (8 shuffles); every lane writes 2 dims.
__global__ __launch_bounds__(256) void agg1_kernel(const unsigned int* __restrict__ h1f8,
                                                   const float* __restrict__ a_src,
                                                   const float* __restrict__ a_dst,
                                                   const int* __restrict__ rowptr,
                                                   const int* __restrict__ esrc,
                                                   const float* __restrict__ b1,
                                                   float* __restrict__ hout) {
    int wid = (blockIdx.x * 256 + threadIdx.x) >> 6;   // node id (wave-uniform)
    if (wid >= N_NODES) return;
    const int lane = threadIdx.x & 63;
    const int m  = lane & 15;        // dim octet: dims 8m..8m+7
    const int gq = lane >> 4;        // edge group 0..3
    const int h  = m >> 1;           // head
    const float ad = a_dst[wid * 8 + h];
    const uint2* __restrict__ hq = reinterpret_cast<const uint2*>(h1f8);  // 16 uint2/node

    float v[8];
    #pragma unroll
    for (int i = 0; i < 8; ++i) v[i] = 0.f;
    float den = 0.f;

    int j = rowptr[wid];
    const int jend = rowptr[wid + 1];
    for (; j + 8 <= jend; j += 8) {
        int s0 = esrc[j + gq];
        int s1 = esrc[j + 4 + gq];
        uint2 u0 = hq[(size_t)s0 * 16 + m];
        uint2 u1 = hq[(size_t)s1 * 16 + m];
        float e0 = a_src[s0 * 8 + h];
        float e1 = a_src[s1 * 8 + h];
        float p0 = __expf(lrelu(e0 + ad));
        float p1 = __expf(lrelu(e1 + ad));
        den += p0 + p1;
        f32x2 c0 = __builtin_amdgcn_cvt_pk_f32_fp8(u0.x, false);
        f32x2 c1 = __builtin_amdgcn_cvt_pk_f32_fp8(u0.x, true);
        f32x2 c2 = __builtin_amdgcn_cvt_pk_f32_fp8(u0.y, false);
        f32x2 c3 = __builtin_amdgcn_cvt_pk_f32_fp8(u0.y, true);
        v[0] = fmaf(p0, c0[0], v[0]); v[1] = fmaf(p0, c0[1], v[1]);
        v[2] = fmaf(p0, c1[0], v[2]); v[3] = fmaf(p0, c1[1], v[3]);
        v[4] = fmaf(p0, c2[0], v[4]); v[5] = fmaf(p0, c2[1], v[5]);
        v[6] = fmaf(p0, c3[0], v[6]); v[7] = fmaf(p0, c3[1], v[7]);
        f32x2 d0 = __builtin_amdgcn_cvt_pk_f32_fp8(u1.x, false);
        f32x2 d1 = __builtin_amdgcn_cvt_pk_f32_fp8(u1.x, true);
        f32x2 d2 = __builtin_amdgcn_cvt_pk_f32_fp8(u1.y, false);
        f32x2 d3 = __builtin_amdgcn_cvt_pk_f32_fp8(u1.y, true);
        v[0] = fmaf(p1, d0[0], v[0]); v[1] = fmaf(p1, d0[1], v[1]);
        v[2] = fmaf(p1, d1[0], v[2]); v[3] = fmaf(p1, d1[1], v[3]);
        v[4] = fmaf(p1, d2[0], v[4]); v[5] = fmaf(p1, d2[1], v[5]);
        v[6] = fmaf(p1, d3[0], v[6]); v[7] = fmaf(p1, d3[1], v[7]);
    }
    if (j + 4 <= jend) {
        int s = esrc[j + gq];
        uint2 u = hq[(size_t)s * 16 + m];
        float e = a_src[s * 8 + h];
        float p = __expf(lrelu(e + ad));
        den += p;
        f32x2 c0 = __builtin_amdgcn_cvt_pk_f32_fp8(u.x, false);
        f32x2 c1 = __builtin_amdgcn_cvt_pk_f32_fp8(u.x, true);
        f32x2 c2 = __builtin_amdgcn_cvt_pk_f32_fp8(u.y, false);
        f32x2 c3 = __builtin_amdgcn_cvt_pk_f32_fp8(u.y, true);
        v[0] = fmaf(p, c0[0], v[0]); v[1] = fmaf(p, c0[1], v[1]);
        v[2] = fmaf(p, c1[0], v[2]); v[3] = fmaf(p, c1[1], v[3]);
        v[4] = fmaf(p, c2[0], v[4]); v[5] = fmaf(p, c2[1], v[5]);
        v[6] = fmaf(p, c3[0], v[6]); v[7] = fmaf(p, c3[1], v[7]);
        j += 4;
    }
    if (j + gq < jend) {             // tail: <=3 edges, group gq takes edge j+gq
        int s = esrc[j + gq];
        uint2 u = hq[(size_t)s * 16 + m];
        float e = a_src[s * 8 + h];
        float p = __expf(lrelu(e + ad));
        den += p;
        f32x2 c0 = __builtin_amdgcn_cvt_pk_f32_fp8(u.x, false);
        f32x2 c1 = __builtin_amdgcn_cvt_pk_f32_fp8(u.x, true);
        f32x2 c2 = __builtin_amdgcn_cvt_pk_f32_fp8(u.y, false);
        f32x2 c3 = __builtin_amdgcn_cvt_pk_f32_fp8(u.y, true);
        v[0] = fmaf(p, c0[0], v[0]); v[1] = fmaf(p, c0[1], v[1]);
        v[2] = fmaf(p, c1[0], v[2]); v[3] = fmaf(p, c1[1], v[3]);
        v[4] = fmaf(p, c2[0], v[4]); v[5] = fmaf(p, c2[1], v[5]);
        v[6] = fmaf(p, c3[0], v[6]); v[7] = fmaf(p, c3[1], v[7]);
    }

    // reduce-scatter butterfly across the 4 edge groups (same m => same dims/head)
    const int g1 = (lane >> 4) & 1;
    const int g2 = lane >> 5;
    float k4[4];
    #pragma unroll
    for (int i = 0; i < 4; ++i) {
        float send = g1 ? v[i] : v[4 + i];
        float recv = __shfl_xor(send, 16, 64);
        k4[i] = (g1 ? v[4 + i] : v[i]) + recv;
    }
    float k2[2];
    #pragma unroll
    for (int i = 0; i < 2; ++i) {
        float send = g2 ? k4[i] : k4[2 + i];
        float recv = __shfl_xor(send, 32, 64);
        k2[i] = (g2 ? k4[2 + i] : k4[i]) + recv;
    }
    den += __shfl_xor(den, 16, 64);
    den += __shfl_xor(den, 32, 64);

    const float inv = 1.f / den;
    const int base = 8 * m + 4 * g1 + 2 * g2;    // bijective over even offsets 0..126
    float2 bb = *reinterpret_cast<const float2*>(b1 + base);
    float2 o = make_float2(elu1(k2[0] * inv + bb.x), elu1(k2[1] * inv + bb.y));
    *reinterpret_cast<float2*>(hout + (size_t)wid * F_IN + base) = o;
}

// ---------------- conv2 GEMM + attention scores ----------------
__global__ __launch_bounds__(256) void gemm2_kernel(const float* __restrict__ h,
                                                    const float* __restrict__ W2,
                                                    const float* __restrict__ att_src2,
                                                    const float* __restrict__ att_dst2,
                                                    float* __restrict__ h2,
                                                    float* __restrict__ a_src2,
                                                    float* __restrict__ a_dst2) {
    __shared__ float Ws[F_IN * ND2];     // 4 KB
    __shared__ float Hs[32 * 132];       // padded, ~16.9 KB
    int t = threadIdx.x;
    int node0 = blockIdx.x * 32;
    #pragma unroll
    for (int i = 0; i < 4; ++i) { int idx = i * 256 + t; Ws[idx] = W2[idx]; }
    #pragma unroll
    for (int i = 0; i < 4; ++i) {
        int fidx = i * 256 + t;
        int r = fidx >> 5;
        int c4 = fidx & 31;
        int grow = node0 + r;
        float4 v = make_float4(0.f, 0.f, 0.f, 0.f);
        if (grow < N_NODES) v = *reinterpret_cast<const float4*>(h + (size_t)grow * F_IN + c4 * 4);
        *reinterpret_cast<float4*>(&Hs[r * 132 + c4 * 4]) = v;
    }
    __syncthreads();
    int nsub = t >> 3, d = t & 7;
    int node = node0 + nsub;
    float acc = 0.f;
    #pragma unroll 8
    for (int k = 0; k < F_IN; ++k)
        acc = fmaf(Hs[nsub * 132 + k], Ws[k * ND2 + d], acc);
    float vs = acc * att_src2[d];
    float vd = acc * att_dst2[d];
    #pragma unroll
    for (int off = 4; off >= 1; off >>= 1) {
        vs += __shfl_xor(vs, off, 8);
        vd += __shfl_xor(vd, off, 8);
    }
    if (node < N_NODES) {
        h2[node * ND2 + d] = acc;
        if (d == 0) { a_src2[node] = vs; a_dst2[node] = vd; }
    }
}

// ---------------- conv2 aggregation: one thread per node ----------------
__global__ void agg2_kernel(const float* __restrict__ h2,
                            const float* __restrict__ a_src2, const float* __restrict__ a_dst2,
                            const int* __restrict__ rowptr, const int* __restrict__ esrc,
                            const float* __restrict__ b2, float* __restrict__ g) {
    int n = blockIdx.x * blockDim.x + threadIdx.x;
    if (n >= N_NODES) return;
    float ad = a_dst2[n];
    float acc[8] = {0.f, 0.f, 0.f, 0.f, 0.f, 0.f, 0.f, 0.f};
    float den = 0.f;
    int jend = rowptr[n + 1];
    for (int j = rowptr[n]; j < jend; ++j) {
        int s = esrc[j];
        float p = __expf(lrelu(a_src2[s] + ad));
        den += p;
        float4 va = *reinterpret_cast<const float4*>(h2 + s * ND2);
        float4 vb = *reinterpret_cast<const float4*>(h2 + s * ND2 + 4);
        acc[0] = fmaf(p, va.x, acc[0]); acc[1] = fmaf(p, va.y, acc[1]);
        acc[2] = fmaf(p, va.z, acc[2]); acc[3] = fmaf(p, va.w, acc[3]);
        acc[4] = fmaf(p, vb.x, acc[4]); acc[5] = fmaf(p, vb.y, acc[5]);
        acc[6] = fmaf(p, vb.z, acc[6]); acc[7] = fmaf(p, vb.w, acc[7]);
    }
    float inv = 1.f / den;
    float4 o0 = make_float4(elu1(acc[0] * inv + b2[0]), elu1(acc[1] * inv + b2[1]),
                            elu1(acc[2] * inv + b2[2]), elu1(acc[3] * inv + b2[3]));
    float4 o1 = make_float4(elu1(acc[4] * inv + b2[4]), elu1(acc[5] * inv + b2[5]),
                            elu1(acc[6] * inv + b2[6]), elu1(acc[7] * inv + b2[7]));
    *reinterpret_cast<float4*>(g + n * ND2)     = o0;
    *reinterpret_cast<float4*>(g + n * ND2 + 4) = o1;
}

// ---------------- fc1 stage 1: 1667 blocks x 240 rows, 4-deep float4, no atomics -------
__global__ __launch_bounds__(256) void fc1_stage1(const float* __restrict__ z,
                                                  const float* __restrict__ w,
                                                  float* __restrict__ partial) {
    __shared__ float zs[FC1_RPB];
    __shared__ float4 red[252];
    const int t = threadIdx.x;
    const int b = blockIdx.x;
    const int r0 = b * FC1_RPB;
    if (t < FC1_RPB) {
        int gr = r0 + t;
        zs[t] = (gr < ZLEN) ? z[gr] : 0.f;
    }
    __syncthreads();
    const int c4 = t % 21;
    const int rr = t / 21;
    if (t < 252) {
        float4 a = make_float4(0.f, 0.f, 0.f, 0.f);
        const float4* __restrict__ w4 = reinterpret_cast<const float4*>(w);
        if (r0 + FC1_RPB <= ZLEN) {
            #pragma unroll
            for (int bq = 0; bq < 5; ++bq) {
                float4 wv[4];
                float  zv[4];
                #pragma unroll
                for (int u = 0; u < 4; ++u) {
                    int i = bq * 48 + u * 12 + rr;
                    wv[u] = w4[(size_t)(r0 + i) * 21 + c4];
                    zv[u] = zs[i];
                }
                #pragma unroll
                for (int u = 0; u < 4; ++u) {
                    a.x = fmaf(zv[u], wv[u].x, a.x);
                    a.y = fmaf(zv[u], wv[u].y, a.y);
                    a.z = fmaf(zv[u], wv[u].z, a.z);
                    a.w = fmaf(zv[u], wv[u].w, a.w);
                }
            }
        } else {
            for (int i = rr; i < FC1_RPB; i += 12) {
                if (r0 + i < ZLEN) {
                    float4 wv = w4[(size_t)(r0 + i) * 21 + c4];
                    float  zv = zs[i];
                    a.x = fmaf(zv, wv.x, a.x); a.y = fmaf(zv, wv.y, a.y);
                    a.z = fmaf(zv, wv.z, a.z); a.w = fmaf(zv, wv.w, a.w);
                }
            }
        }
        red[t] = a;
    }
    __syncthreads();
    if (t < 21) {
        float4 s = red[t];
        #pragma unroll
        for (int k = 1; k < 12; ++k) {
            float4 v = red[k * 21 + t];
            s.x += v.x; s.y += v.y; s.z += v.z; s.w += v.w;
        }
        *reinterpret_cast<float4*>(partial + (size_t)b * 88 + t * 4) = s;
    }
}

// ---------------- tail: reduce 1667 partials + MLP + log_softmax ----------------
__global__ __launch_bounds__(1024) void fctail_kernel(const float* __restrict__ partial,
                                                      const float* __restrict__ fc1_b,
                                                      const float* __restrict__ fc2_w,
                                                      const float* __restrict__ fc2_b,
                                                      const float* __restrict__ fc3_w,
                                                      const float* __restrict__ fc3_b,
                                                      float* __restrict__ out) {
    __shared__ float red[1008];
    __shared__ float z1[84];
    __shared__ float z2[24];
    const int t = threadIdx.x;
    if (t < 1008) {
        const int j  = t % 84;
        const int sl = t / 84;          // 0..11
        float s = 0.f;
        for (int b = sl; b < FC1_NB; b += 12)
            s += partial[(size_t)b * 88 + j];
        red[t] = s;
    }
    __syncthreads();
    if (t < 84) {
        float s = 0.f;
        #pragma unroll
        for (int sl = 0; sl < 12; ++sl) s += red[sl * 84 + t];
        z1[t] = elu1(s + fc1_b[t]);
    }
    __syncthreads();
    if (t < 24) {
        float a = fc2_b[t];
        for (int i = 0; i < 84; ++i) a = fmaf(z1[i], fc2_w[i * 24 + t], a);
        z2[t] = elu1(a);
    }
    __syncthreads();
    if (t == 0) {
        float z3[2];
        #pragma unroll
        for (int jj = 0; jj < 2; ++jj) {
            float a = fc3_b[jj];
            for (int i = 0; i < 24; ++i) a = fmaf(z2[i], fc3_w[i * 2 + jj], a);
            z3[jj] = a;
        }
        float m = fmaxf(z3[0], z3[1]);
        float l = m + logf(__expf(z3[0] - m) + __expf(z3[1] - m));
        out[0] = z3[0] - l;
        out[1] = z3[1] - l;
    }
}

extern "C" void kernel_launch(void* const* d_in, const int* in_sizes, int n_in,
                              void* d_out, int out_size, void* d_ws, size_t ws_size,
                              hipStream_t stream) {
    const float* x        = (const float*)d_in[0];
    const int*   ei       = (const int*)d_in[1];
    const float* W1       = (const float*)d_in[2];
    const float* att_src1 = (const float*)d_in[3];
    const float* att_dst1 = (const float*)d_in[4];
    const float* b1       = (const float*)d_in[5];
    const float* W2       = (const float*)d_in[6];
    const float* att_src2 = (const float*)d_in[7];
    const float* att_dst2 = (const float*)d_in[8];
    const float* b2       = (const float*)d_in[9];
    const float* fc1_w    = (const float*)d_in[10];
    const float* fc1_b    = (const float*)d_in[11];
    const float* fc2_w    = (const float*)d_in[12];
    const float* fc2_b    = (const float*)d_in[13];
    const float* fc3_w    = (const float*)d_in[14];
    const float* fc3_b    = (const float*)d_in[15];
    float* out = (float*)d_out;

    char* ws = (char*)d_ws;
    unsigned int* h1f8 = (unsigned int*)(ws + 0);        // 6,400,000 B (fp8 x 128 per node)
    float* hbuf   = (float*)(ws + 6400000);              // 25,600,000 B
    float* a_src1 = (float*)(ws + 32000000);             // 1,600,000 B
    float* a_dst1 = (float*)(ws + 33600000);             // 1,600,000 B
    float* h2     = (float*)(ws + 35200000);             // 1,600,000 B
    float* a_src2 = (float*)(ws + 36800000);             // 200,000 B
    float* a_dst2 = (float*)(ws + 37000000);             // 200,000 B
    float* g      = (float*)(ws + 37200000);             // 1,600,000 B
    int*   counts = (int*)  (ws + 38800000);             // 200,000 B
    int*   rowptr = (int*)  (ws + 39000000);             // 200,064 B
    int*   cursor = (int*)  (ws + 39200064);             // 200,000 B
    int*   esrc   = (int*)  (ws + 39400064);             // 3,400,000 B
    float* partial= (float*)(ws + 42800064);             // 1667*88*4 = 586,784 B
    uint4* wbf    = (uint4*)(ws + 43386848);             // 32,768 B
    int*   bsum   = (int*)  (ws + 43419616);             // 784 B

    prep_kernel<<<NBLK, 256, 0, stream>>>(W1, wbf, counts);
    hist_kernel<<<(NE / 4 + 255) / 256, 256, 0, stream>>>(ei, counts);
    scan1_kernel<<<NBLK, 256, 0, stream>>>(counts, bsum);
    scan3_kernel<<<NBLK, 256, 0, stream>>>(counts, bsum, rowptr, cursor);
    fill_kernel<<<(NE / 4 + N_NODES + 255) / 256, 256, 0, stream>>>(ei, cursor, esrc);

    gemm1_kernel<<<(N_NODES + 63) / 64, 256, 0, stream>>>(x, wbf, att_src1, att_dst1, h1f8, a_src1, a_dst1);
    agg1_kernel<<<(N_NODES + 3) / 4, 256, 0, stream>>>(h1f8, a_src1, a_dst1, rowptr, esrc, b1, hbuf);

    gemm2_kernel<<<(N_NODES + 31) / 32, 256, 0, stream>>>(hbuf, W2, att_src2, att_dst2, h2, a_src2, a_dst2);
    agg2_kernel<<<(N_NODES + 255) / 256, 256, 0, stream>>>(h2, a_src2, a_dst2, rowptr, esrc, b2, g);

    fc1_stage1<<<FC1_NB, 256, 0, stream>>>(g, fc1_w, partial);
    fctail_kernel<<<1, 1024, 0, stream>>>(partial, fc1_b, fc2_w, fc2_b, fc3_w, fc3_b, out);
}